// Round 2
// baseline (401.463 us; speedup 1.0000x reference)
//
#include <hip/hip_runtime.h>
#include <hip/hip_bf16.h>

#define B_ 128
#define L_ 128
#define J_ 64
#define E_ 128
#define H_ 2
#define HD 64
#define S_ 129          // L+1
#define M_ (B_ * S_)    // 16512 tokens
#define CAT_ 1000
#define LN_EPS 1e-5f
#define QCHUNK 43       // 129 = 3*43 query chunks per (b,h)

// ---------------------------------------------------------------------------
// Embedding: x[b,0,:] = id_table[id]; x[b,1+l,:] = sum_j mask*(cat+amt) + dt
// ---------------------------------------------------------------------------
__global__ __launch_bounds__(128)
void embed_kernel(const int* __restrict__ cat_arr, const int* __restrict__ dt_arr,
                  const int* __restrict__ amount_arr, const int* __restrict__ id_arr,
                  const float* __restrict__ id_table, const float* __restrict__ cat_table,
                  const float* __restrict__ amount_table, const float* __restrict__ dt_table,
                  float* __restrict__ x) {
    const int blk = blockIdx.x;
    const int b = blk / S_;
    const int s = blk % S_;
    const int e = threadIdx.x;
    if (s == 0) {
        const int id = id_arr[b];
        x[(size_t)(b * S_) * E_ + e] = id_table[(size_t)id * E_ + e];
        return;
    }
    const int l = s - 1;
    __shared__ int cs[J_];
    __shared__ int as_[J_];
    if (threadIdx.x < J_) cs[threadIdx.x] = cat_arr[((size_t)b * L_ + l) * J_ + threadIdx.x];
    else as_[threadIdx.x - J_] = amount_arr[((size_t)b * L_ + l) * J_ + threadIdx.x - J_];
    __syncthreads();
    float acc = 0.f;
    #pragma unroll 4
    for (int j = 0; j < J_; ++j) {
        const int c = cs[j];
        if (c != CAT_) {   // uniform across the block
            acc += cat_table[(size_t)c * E_ + e] + amount_table[(size_t)as_[j] * E_ + e];
        }
    }
    acc += dt_table[(size_t)dt_arr[b * L_ + l] * E_ + e];
    x[((size_t)b * S_ + s) * E_ + e] = acc;
}

// ---------------------------------------------------------------------------
// Generic f32 tiled GEMM: C = A[M,K] @ B[K,N] (+bias) (+resid) (relu?)
// OutT in {float, __hip_bfloat16}. blockIdx.z>1 => split-K partials (f32).
// ---------------------------------------------------------------------------
template<int BM, int BN, int BK, int TM, int TN, bool RELU, typename OutT>
__global__ __launch_bounds__((BM / TM) * (BN / TN))
void gemm_bias(const float* __restrict__ A, const float* __restrict__ Bm,
               const float* __restrict__ bias, const float* __restrict__ resid,
               OutT* __restrict__ C, int M, int N, int K) {
    static_assert(TM == 4 && TN == 4, "float4 micro-tile");
    constexpr int NT = (BM / TM) * (BN / TN);
    constexpr int TX = BN / TN;
    __shared__ __align__(16) float As[BK][BM + 4];
    __shared__ __align__(16) float Bs[BK][BN + 4];
    const int tid = threadIdx.x;
    const int tx = tid % TX, ty = tid / TX;
    const int m0 = blockIdx.x * BM, n0 = blockIdx.y * BN;
    const int z = blockIdx.z;
    const int kchunk = (K + gridDim.z - 1) / gridDim.z;
    const int kbeg = z * kchunk;
    const int kend = min(K, kbeg + kchunk);

    float acc[TM][TN] = {};
    for (int k0 = kbeg; k0 < kend; k0 += BK) {
        for (int idx = tid; idx < BM * BK; idx += NT) {
            const int m = idx / BK, kk = idx % BK;
            const int gm = m0 + m, gk = k0 + kk;
            As[kk][m] = (gm < M && gk < kend) ? A[(size_t)gm * K + gk] : 0.f;
        }
        for (int idx = tid; idx < BK * BN; idx += NT) {
            const int kk = idx / BN, n = idx % BN;
            const int gk = k0 + kk, gn = n0 + n;
            Bs[kk][n] = (gk < kend && gn < N) ? Bm[(size_t)gk * N + gn] : 0.f;
        }
        __syncthreads();
        #pragma unroll 4
        for (int kk = 0; kk < BK; ++kk) {
            const float4 a4 = *(const float4*)&As[kk][ty * TM];
            const float4 b4 = *(const float4*)&Bs[kk][tx * TN];
            const float a[4] = {a4.x, a4.y, a4.z, a4.w};
            const float b[4] = {b4.x, b4.y, b4.z, b4.w};
            #pragma unroll
            for (int i = 0; i < TM; ++i)
                #pragma unroll
                for (int j = 0; j < TN; ++j)
                    acc[i][j] = fmaf(a[i], b[j], acc[i][j]);
        }
        __syncthreads();
    }

    OutT* Cp = C + (size_t)z * M * N;
    #pragma unroll
    for (int i = 0; i < TM; ++i) {
        const int gm = m0 + ty * TM + i;
        if (gm >= M) continue;
        #pragma unroll
        for (int j = 0; j < TN; ++j) {
            const int gn = n0 + tx * TN + j;
            if (gn >= N) continue;
            float vv = acc[i][j];
            if (bias) vv += bias[gn];
            if (resid) vv += resid[(size_t)gm * N + gn];
            if (RELU) vv = fmaxf(vv, 0.f);
            Cp[(size_t)gm * N + gn] = (OutT)vv;
        }
    }
}

// ---------------------------------------------------------------------------
// Attention: one block per (b, head, query-chunk of 43). K/V are bf16.
// Output o is written IN-PLACE into the q buffer (each block reads only its
// own q rows+head-cols into LDS before any write; no cross-block aliasing).
// ---------------------------------------------------------------------------
__global__ __launch_bounds__(256)
void attn_kernel(float* __restrict__ q, const __hip_bfloat16* __restrict__ kg,
                 const __hip_bfloat16* __restrict__ vg) {
    __shared__ float q_lds[44][65];
    __shared__ float kv[129][65];     // K first, then reloaded with V
    __shared__ float sc[44][133];
    const int tid = threadIdx.x;
    const int blk = blockIdx.x;
    const int qc = blk % 3;
    const int h = (blk / 3) & (H_ - 1);
    const int b = blk / (3 * H_);
    const int q0 = qc * QCHUNK;
    const size_t base = ((size_t)b * S_) * E_ + h * HD;

    for (int idx = tid; idx < QCHUNK * HD; idx += 256) {
        const int r = idx >> 6, d = idx & 63;
        q_lds[r][d] = q[base + (size_t)(q0 + r) * E_ + d];
    }
    for (int idx = tid; idx < S_ * HD; idx += 256) {
        const int t = idx >> 6, d = idx & 63;
        kv[t][d] = __bfloat162float(kg[base + (size_t)t * E_ + d]);
    }
    __syncthreads();

    // scores = q @ k^T * 0.125 ; 4-row register blocking
    for (int idx = tid; idx < 11 * S_; idx += 256) {
        const int rq = idx / S_, t = idx - rq * S_;
        float a0 = 0, a1 = 0, a2 = 0, a3 = 0;
        #pragma unroll 8
        for (int kk = 0; kk < HD; ++kk) {
            const float kvv = kv[t][kk];
            a0 = fmaf(q_lds[rq][kk], kvv, a0);
            a1 = fmaf(q_lds[rq + 11][kk], kvv, a1);
            a2 = fmaf(q_lds[rq + 22][kk], kvv, a2);
            a3 = fmaf(q_lds[rq + 33][kk], kvv, a3);
        }
        sc[rq][t] = a0 * 0.125f;
        sc[rq + 11][t] = a1 * 0.125f;
        sc[rq + 22][t] = a2 * 0.125f;
        if (rq + 33 < QCHUNK) sc[rq + 33][t] = a3 * 0.125f;
    }
    __syncthreads();

    // reload kv with V while threads<43 run row softmax on sc
    for (int idx = tid; idx < S_ * HD; idx += 256) {
        const int t = idx >> 6, d = idx & 63;
        kv[t][d] = __bfloat162float(vg[base + (size_t)t * E_ + d]);
    }
    if (tid < QCHUNK) {
        float mx = -1e30f;
        for (int t = 0; t < S_; ++t) mx = fmaxf(mx, sc[tid][t]);
        float lsum = 0.f;
        for (int t = 0; t < S_; ++t) { const float p = __expf(sc[tid][t] - mx); sc[tid][t] = p; lsum += p; }
        const float inv = 1.f / lsum;
        for (int t = 0; t < S_; ++t) sc[tid][t] *= inv;
    }
    __syncthreads();

    // o = p @ v ; write in-place into q
    for (int idx = tid; idx < 11 * HD; idx += 256) {
        const int rq = idx >> 6, d = idx & 63;
        float a0 = 0, a1 = 0, a2 = 0, a3 = 0;
        for (int t = 0; t < S_; ++t) {
            const float vv = kv[t][d];
            a0 = fmaf(sc[rq][t], vv, a0);
            a1 = fmaf(sc[rq + 11][t], vv, a1);
            a2 = fmaf(sc[rq + 22][t], vv, a2);
            a3 = fmaf(sc[rq + 33][t], vv, a3);
        }
        q[base + (size_t)(q0 + rq) * E_ + d] = a0;
        q[base + (size_t)(q0 + rq + 11) * E_ + d] = a1;
        q[base + (size_t)(q0 + rq + 22) * E_ + d] = a2;
        if (rq + 33 < QCHUNK) q[base + (size_t)(q0 + rq + 33) * E_ + d] = a3;
    }
}

// ---------------------------------------------------------------------------
// LayerNorm over E=128. 4 rows/block.
// ---------------------------------------------------------------------------
__global__ __launch_bounds__(256)
void ln_kernel(const float* __restrict__ X, const float* __restrict__ g,
               const float* __restrict__ bt, float* __restrict__ Y, int M) {
    const int row = blockIdx.x * 4 + (threadIdx.x >> 6);
    const int lane = threadIdx.x & 63;
    if (row >= M) return;
    const float* xr = X + (size_t)row * E_;
    const float v0 = xr[lane], v1 = xr[lane + 64];
    float s = v0 + v1;
    #pragma unroll
    for (int off = 1; off < 64; off <<= 1) s += __shfl_xor(s, off);
    const float mu = s * (1.f / 128.f);
    const float d0 = v0 - mu, d1 = v1 - mu;
    float vs = d0 * d0 + d1 * d1;
    #pragma unroll
    for (int off = 1; off < 64; off <<= 1) vs += __shfl_xor(vs, off);
    const float rstd = rsqrtf(vs * (1.f / 128.f) + LN_EPS);
    float* yr = Y + (size_t)row * E_;
    yr[lane] = d0 * rstd * g[lane] + bt[lane];
    yr[lane + 64] = d1 * rstd * g[lane + 64] + bt[lane + 64];
}

// mean-pool tokens 1..128 -> h[B,E]
__global__ __launch_bounds__(128)
void pool_kernel(const float* __restrict__ X2, float* __restrict__ Hout) {
    const int b = blockIdx.x, e = threadIdx.x;
    float acc = 0.f;
    for (int s = 1; s < S_; ++s) acc += X2[((size_t)b * S_ + s) * E_ + e];
    Hout[(size_t)b * E_ + e] = acc * (1.f / 128.f);
}

__global__ __launch_bounds__(256)
void splitk_reduce(const float* __restrict__ part, const float* __restrict__ bias,
                   float* __restrict__ out, int MN, int N, int parts) {
    const int i = blockIdx.x * blockDim.x + threadIdx.x;
    if (i >= MN) return;
    float v = bias[i % N];
    for (int z = 0; z < parts; ++z) v += part[(size_t)z * MN + i];
    out[i] = v;
}

// ---------------------------------------------------------------------------
extern "C" void kernel_launch(void* const* d_in, const int* in_sizes, int n_in,
                              void* d_out, int out_size, void* d_ws, size_t ws_size,
                              hipStream_t stream) {
    const int* cat_arr      = (const int*)d_in[0];
    const int* dt_arr       = (const int*)d_in[1];
    const int* amount_arr   = (const int*)d_in[2];
    const int* id_arr       = (const int*)d_in[3];
    const float* id_table   = (const float*)d_in[4];
    const float* cat_table  = (const float*)d_in[5];
    const float* amount_tab = (const float*)d_in[6];
    const float* dt_table   = (const float*)d_in[7];
    const float* Wq = (const float*)d_in[8];  const float* bq = (const float*)d_in[9];
    const float* Wk = (const float*)d_in[10]; const float* bk = (const float*)d_in[11];
    const float* Wv = (const float*)d_in[12]; const float* bv = (const float*)d_in[13];
    const float* Wo = (const float*)d_in[14]; const float* bo = (const float*)d_in[15];
    const float* ln1_g = (const float*)d_in[16]; const float* ln1_b = (const float*)d_in[17];
    const float* W1 = (const float*)d_in[18]; const float* b1 = (const float*)d_in[19];
    const float* W2 = (const float*)d_in[20]; const float* b2 = (const float*)d_in[21];
    const float* ln2_g = (const float*)d_in[22]; const float* ln2_b = (const float*)d_in[23];
    const float* lin1_W = (const float*)d_in[24]; const float* lin1_b = (const float*)d_in[25];
    const float* lin2_W = (const float*)d_in[26]; const float* lin2_b = (const float*)d_in[27];
    float* out = (float*)d_out;
    float* ws = (float*)d_ws;

    // Compact layout: 3*ME floats total (~24.2 MiB).
    const size_t ME = (size_t)M_ * E_;      // 2,113,536
    float* X  = ws;                          // x  -> later: x1 (ln1), x2 (ln2)
    float* Q  = ws + ME;                     // q  -> o (in-place) -> ff1 -> tail
    float* KVr = ws + 2 * ME;                // bf16 k | bf16 v  -> f32 post1/post2
    __hip_bfloat16* Kb = (__hip_bfloat16*)KVr;
    __hip_bfloat16* Vb = (__hip_bfloat16*)(ws + 2 * ME + ME / 2);
    float* P1 = KVr;                         // f32 [M,E] reuse of kv region
    // tail aliases Q (dead after FF2): hb + a1 + prt = 1,168,384 floats < ME
    float* hb  = Q;                          // [B,E]
    float* a1  = Q + (size_t)B_ * E_;        // [B,CAT]
    float* prt = a1 + (size_t)B_ * CAT_;     // [8,B,CAT]

    embed_kernel<<<M_, 128, 0, stream>>>(cat_arr, dt_arr, amount_arr, id_arr,
                                         id_table, cat_table, amount_tab, dt_table, X);

    const dim3 gE(M_ / 64, E_ / 64, 1);     // 258 x 2
    gemm_bias<64, 64, 32, 4, 4, false, float>
        <<<gE, 256, 0, stream>>>(X, Wq, bq, nullptr, Q, M_, E_, E_);
    gemm_bias<64, 64, 32, 4, 4, false, __hip_bfloat16>
        <<<gE, 256, 0, stream>>>(X, Wk, bk, nullptr, Kb, M_, E_, E_);
    gemm_bias<64, 64, 32, 4, 4, false, __hip_bfloat16>
        <<<gE, 256, 0, stream>>>(X, Wv, bv, nullptr, Vb, M_, E_, E_);

    attn_kernel<<<B_ * H_ * 3, 256, 0, stream>>>(Q, Kb, Vb);   // o -> Q

    // P1 = x + o@Wo + bo (kv region now dead); then LN1 -> X (x dead after resid)
    gemm_bias<64, 64, 32, 4, 4, false, float>
        <<<gE, 256, 0, stream>>>(Q, Wo, bo, X, P1, M_, E_, E_);
    ln_kernel<<<M_ / 4, 256, 0, stream>>>(P1, ln1_g, ln1_b, X, M_);
    // ff1 = relu(X@W1+b1) -> Q ; P1 = X + ff1@W2 + b2 ; LN2 -> X
    gemm_bias<64, 64, 32, 4, 4, true, float>
        <<<gE, 256, 0, stream>>>(X, W1, b1, nullptr, Q, M_, E_, E_);
    gemm_bias<64, 64, 32, 4, 4, false, float>
        <<<gE, 256, 0, stream>>>(Q, W2, b2, X, P1, M_, E_, E_);
    ln_kernel<<<M_ / 4, 256, 0, stream>>>(P1, ln2_g, ln2_b, X, M_);

    pool_kernel<<<B_, 128, 0, stream>>>(X, hb);

    gemm_bias<64, 64, 32, 4, 4, true, float>
        <<<dim3(2, 16, 1), 256, 0, stream>>>(hb, lin1_W, lin1_b, nullptr, a1, B_, CAT_, E_);
    gemm_bias<64, 64, 32, 4, 4, false, float>
        <<<dim3(2, 16, 8), 256, 0, stream>>>(a1, lin2_W, nullptr, nullptr, prt, B_, CAT_, CAT_);
    splitk_reduce<<<(B_ * CAT_ + 255) / 256, 256, 0, stream>>>(
        prt, lin2_b, out, B_ * CAT_, CAT_, 8);
}

// Round 3
// 251.313 us; speedup vs baseline: 1.5975x; 1.5975x over previous
//
#include <hip/hip_runtime.h>
#include <hip/hip_bf16.h>

#define B_ 128
#define L_ 128
#define J_ 64
#define E_ 128
#define H_ 2
#define HD 64
#define S_ 129          // L+1
#define M_ (B_ * S_)    // 16512 tokens
#define CAT_ 1000
#define LN_EPS 1e-5f
#define QCHUNK 43

typedef __attribute__((ext_vector_type(8))) short bf16x8;
typedef __attribute__((ext_vector_type(4))) float f32x4;
typedef __hip_bfloat16 bf16;

// ---------------------------------------------------------------------------
// prep: transpose+convert all weights to bf16 Bt[N][K]; pad lin1/lin2; pad bias
// Wd bf16 offsets: q=0 k=16384 v=32768 o=49152 w1=65536 w2=81920
//                  lin1=98304 ([1024][128]) lin2=229376 ([1024][1024])
// ---------------------------------------------------------------------------
__global__ __launch_bounds__(256)
void prep_kernel(const float* __restrict__ Wq, const float* __restrict__ Wk,
                 const float* __restrict__ Wv, const float* __restrict__ Wo,
                 const float* __restrict__ W1, const float* __restrict__ W2,
                 const float* __restrict__ lin1W, const float* __restrict__ lin2W,
                 const float* __restrict__ lin1b,
                 bf16* __restrict__ Wd, float* __restrict__ bias1024) {
    const int z = blockIdx.z;
    const float* src; bf16* dst; int Kd, Nd, sK, sN;
    switch (z) {
        case 0: src = Wq;    dst = Wd;          Kd = 128;  Nd = 128;  sK = 128;  sN = 128;  break;
        case 1: src = Wk;    dst = Wd + 16384;  Kd = 128;  Nd = 128;  sK = 128;  sN = 128;  break;
        case 2: src = Wv;    dst = Wd + 32768;  Kd = 128;  Nd = 128;  sK = 128;  sN = 128;  break;
        case 3: src = Wo;    dst = Wd + 49152;  Kd = 128;  Nd = 128;  sK = 128;  sN = 128;  break;
        case 4: src = W1;    dst = Wd + 65536;  Kd = 128;  Nd = 128;  sK = 128;  sN = 128;  break;
        case 5: src = W2;    dst = Wd + 81920;  Kd = 128;  Nd = 128;  sK = 128;  sN = 128;  break;
        case 6: src = lin1W; dst = Wd + 98304;  Kd = 128;  Nd = 1024; sK = 128;  sN = 1000; break;
        default:src = lin2W; dst = Wd + 229376; Kd = 1024; Nd = 1024; sK = 1000; sN = 1000; break;
    }
    if (z == 7 && blockIdx.x == 0 && blockIdx.y == 0) {
        for (int i = threadIdx.x; i < 1024; i += 256)
            bias1024[i] = (i < 1000) ? lin1b[i] : 0.f;
    }
    const int k0 = blockIdx.x * 64, n0 = blockIdx.y * 64;
    if (k0 >= Kd || n0 >= Nd) return;
    __shared__ float t[64][65];
    const int c = threadIdx.x & 63, r0 = threadIdx.x >> 6;
    #pragma unroll 4
    for (int i = 0; i < 16; ++i) {
        const int r = r0 + i * 4;
        const int gk = k0 + r, gn = n0 + c;
        t[r][c] = (gk < sK && gn < sN) ? src[(size_t)gk * sN + gn] : 0.f;
    }
    __syncthreads();
    #pragma unroll 4
    for (int i = 0; i < 16; ++i) {
        const int r = r0 + i * 4;
        dst[(size_t)(n0 + r) * Kd + (k0 + c)] = __float2bfloat16(t[c][r]);
    }
}

// ---------------------------------------------------------------------------
// Embedding: writes f32 X (residual) and bf16 Xb (GEMM A operand)
// ---------------------------------------------------------------------------
__global__ __launch_bounds__(128)
void embed_kernel(const int* __restrict__ cat_arr, const int* __restrict__ dt_arr,
                  const int* __restrict__ amount_arr, const int* __restrict__ id_arr,
                  const float* __restrict__ id_table, const float* __restrict__ cat_table,
                  const float* __restrict__ amount_table, const float* __restrict__ dt_table,
                  float* __restrict__ x, bf16* __restrict__ xb) {
    const int blk = blockIdx.x;
    const int b = blk / S_;
    const int s = blk % S_;
    const int e = threadIdx.x;
    const size_t off = ((size_t)b * S_ + s) * E_ + e;
    if (s == 0) {
        const float v = id_table[(size_t)id_arr[b] * E_ + e];
        x[off] = v; xb[off] = __float2bfloat16(v);
        return;
    }
    const int l = s - 1;
    __shared__ int cs[J_];
    __shared__ int as_[J_];
    if (threadIdx.x < J_) cs[threadIdx.x] = cat_arr[((size_t)b * L_ + l) * J_ + threadIdx.x];
    else as_[threadIdx.x - J_] = amount_arr[((size_t)b * L_ + l) * J_ + threadIdx.x - J_];
    __syncthreads();
    float acc = 0.f;
    #pragma unroll 4
    for (int j = 0; j < J_; ++j) {
        const int c = cs[j];
        if (c != CAT_) {
            acc += cat_table[(size_t)c * E_ + e] + amount_table[(size_t)as_[j] * E_ + e];
        }
    }
    acc += dt_table[(size_t)dt_arr[b * L_ + l] * E_ + e];
    x[off] = acc; xb[off] = __float2bfloat16(acc);
}

// ---------------------------------------------------------------------------
// bf16 MFMA GEMM: C = A[M,K]bf16 @ Bt[N,K]bf16 (+bias)(+resid)(relu|LN)
// BM=64, BN=128, 4 waves x (16 rows x 128 cols). XOR-swizzled LDS.
// Grid: (M/64, Npad/128). Store guard col < Nstore. Strides = Nstride.
// ---------------------------------------------------------------------------
template<bool RELU, bool LN, bool HASRES, bool OF32, bool OBF16>
__global__ __launch_bounds__(256)
void gemm_mfma(const bf16* __restrict__ A, const bf16* __restrict__ Bt,
               const float* __restrict__ bias, const float* __restrict__ resid,
               float* __restrict__ Cf, bf16* __restrict__ Cb,
               const float* __restrict__ lng, const float* __restrict__ lnb,
               int K, int Nstride, int Nstore) {
    __shared__ bf16x8 Al[64 * 16];    // 16 KiB
    __shared__ bf16x8 Bl[128 * 16];   // 32 KiB
    const int tid = threadIdx.x;
    const int m0 = blockIdx.x * 64;
    const int n0 = blockIdx.y * 128;
    const int w = tid >> 6, l = tid & 63;
    const int l15 = l & 15, g = l >> 4;
    f32x4 acc[8] = {};

    for (int kc = 0; kc < K; kc += 128) {
        #pragma unroll
        for (int i = 0; i < 4; ++i) {
            const int lin = i * 256 + tid;
            const int r = lin >> 4, u = lin & 15;
            Al[r * 16 + (u ^ (r & 7))] =
                *(const bf16x8*)(A + (size_t)(m0 + r) * K + kc + u * 8);
        }
        #pragma unroll
        for (int i = 0; i < 8; ++i) {
            const int lin = i * 256 + tid;
            const int r = lin >> 4, u = lin & 15;
            Bl[r * 16 + (u ^ (r & 7))] =
                *(const bf16x8*)(Bt + (size_t)(n0 + r) * K + kc + u * 8);
        }
        __syncthreads();
        const int mr = w * 16 + l15;
        #pragma unroll
        for (int s = 0; s < 4; ++s) {
            const int ua = s * 4 + g;
            const bf16x8 a = Al[mr * 16 + (ua ^ (mr & 7))];
            #pragma unroll
            for (int nf = 0; nf < 8; ++nf) {
                const int nr = nf * 16 + l15;
                const bf16x8 b = Bl[nr * 16 + (ua ^ (nr & 7))];
                acc[nf] = __builtin_amdgcn_mfma_f32_16x16x32_bf16(a, b, acc[nf], 0, 0, 0);
            }
        }
        __syncthreads();
    }

    // epilogue: lane l owns rows w*16+g*4+fr, cols nf*16+l15
    #pragma unroll
    for (int fr = 0; fr < 4; ++fr) {
        const int grow = m0 + w * 16 + g * 4 + fr;
        float v[8];
        float s1 = 0.f, s2 = 0.f;
        #pragma unroll
        for (int nf = 0; nf < 8; ++nf) {
            const int col = n0 + nf * 16 + l15;
            float xv = acc[nf][fr];
            if (col < Nstore) xv += bias[col];
            if (HASRES) xv += resid[(size_t)grow * Nstride + col];
            if (RELU) xv = fmaxf(xv, 0.f);
            v[nf] = xv;
            if (LN) { s1 += xv; s2 += xv * xv; }
        }
        if (LN) {
            #pragma unroll
            for (int off = 1; off < 16; off <<= 1) {
                s1 += __shfl_xor(s1, off);
                s2 += __shfl_xor(s2, off);
            }
            const float mu = s1 * (1.f / 128.f);
            const float rstd = rsqrtf(s2 * (1.f / 128.f) - mu * mu + LN_EPS);
            #pragma unroll
            for (int nf = 0; nf < 8; ++nf) {
                const int col = n0 + nf * 16 + l15;
                v[nf] = (v[nf] - mu) * rstd * lng[col] + lnb[col];
            }
        }
        #pragma unroll
        for (int nf = 0; nf < 8; ++nf) {
            const int col = n0 + nf * 16 + l15;
            if (col < Nstore) {
                if (OF32)  Cf[(size_t)grow * Nstride + col] = v[nf];
                if (OBF16) Cb[(size_t)grow * Nstride + col] = __float2bfloat16(v[nf]);
            }
        }
    }
}

// ---------------------------------------------------------------------------
// Attention: block per (b, head, q-chunk of 43). bf16 q/k/v; wave-parallel
// softmax; output written in-place into qb (block touches only its region).
// ---------------------------------------------------------------------------
__global__ __launch_bounds__(256)
void attn_kernel(bf16* __restrict__ qb, const bf16* __restrict__ kb,
                 const bf16* __restrict__ vb) {
    __shared__ float q_lds[44][65];
    __shared__ float kv[S_][65];
    __shared__ float sc[44][133];
    const int tid = threadIdx.x;
    const int blk = blockIdx.x;
    const int qc = blk % 3;
    const int h = (blk / 3) & (H_ - 1);
    const int b = blk / (3 * H_);
    const int q0 = qc * QCHUNK;
    const size_t base = ((size_t)b * S_) * E_ + h * HD;

    for (int idx = tid; idx < QCHUNK * HD; idx += 256) {
        const int r = idx >> 6, d = idx & 63;
        q_lds[r][d] = __bfloat162float(qb[base + (size_t)(q0 + r) * E_ + d]);
    }
    for (int idx = tid; idx < S_ * HD; idx += 256) {
        const int t = idx >> 6, d = idx & 63;
        kv[t][d] = __bfloat162float(kb[base + (size_t)t * E_ + d]);
    }
    __syncthreads();

    for (int idx = tid; idx < 11 * S_; idx += 256) {
        const int rq = idx / S_, t = idx - rq * S_;
        float a0 = 0, a1 = 0, a2 = 0, a3 = 0;
        #pragma unroll 8
        for (int kk = 0; kk < HD; ++kk) {
            const float kvv = kv[t][kk];
            a0 = fmaf(q_lds[rq][kk], kvv, a0);
            a1 = fmaf(q_lds[rq + 11][kk], kvv, a1);
            a2 = fmaf(q_lds[rq + 22][kk], kvv, a2);
            a3 = fmaf(q_lds[rq + 33][kk], kvv, a3);
        }
        sc[rq][t] = a0 * 0.125f;
        sc[rq + 11][t] = a1 * 0.125f;
        sc[rq + 22][t] = a2 * 0.125f;
        if (rq + 33 < QCHUNK) sc[rq + 33][t] = a3 * 0.125f;
    }
    __syncthreads();

    // V reload (all threads) then wave-parallel softmax (all 4 waves)
    for (int idx = tid; idx < S_ * HD; idx += 256) {
        const int t = idx >> 6, d = idx & 63;
        kv[t][d] = __bfloat162float(vb[base + (size_t)t * E_ + d]);
    }
    {
        const int wv = tid >> 6, lane = tid & 63;
        for (int r = wv; r < QCHUNK; r += 4) {
            const float e0 = sc[r][lane];
            const float e1 = sc[r][lane + 64];
            const float e2 = (lane == 0) ? sc[r][128] : -1e30f;
            float m = fmaxf(fmaxf(e0, e1), e2);
            #pragma unroll
            for (int off = 1; off < 64; off <<= 1) m = fmaxf(m, __shfl_xor(m, off));
            const float p0 = __expf(e0 - m);
            const float p1 = __expf(e1 - m);
            const float p2 = (lane == 0) ? __expf(e2 - m) : 0.f;
            float s = p0 + p1 + p2;
            #pragma unroll
            for (int off = 1; off < 64; off <<= 1) s += __shfl_xor(s, off);
            const float inv = 1.f / s;
            sc[r][lane] = p0 * inv;
            sc[r][lane + 64] = p1 * inv;
            if (lane == 0) sc[r][128] = p2 * inv;
        }
    }
    __syncthreads();

    for (int idx = tid; idx < 11 * HD; idx += 256) {
        const int rq = idx >> 6, d = idx & 63;
        float a0 = 0, a1 = 0, a2 = 0, a3 = 0;
        for (int t = 0; t < S_; ++t) {
            const float vv = kv[t][d];
            a0 = fmaf(sc[rq][t], vv, a0);
            a1 = fmaf(sc[rq + 11][t], vv, a1);
            a2 = fmaf(sc[rq + 22][t], vv, a2);
            a3 = fmaf(sc[rq + 33][t], vv, a3);
        }
        qb[base + (size_t)(q0 + rq) * E_ + d] = __float2bfloat16(a0);
        qb[base + (size_t)(q0 + rq + 11) * E_ + d] = __float2bfloat16(a1);
        qb[base + (size_t)(q0 + rq + 22) * E_ + d] = __float2bfloat16(a2);
        if (rq + 33 < QCHUNK)
            qb[base + (size_t)(q0 + rq + 33) * E_ + d] = __float2bfloat16(a3);
    }
}

// mean-pool tokens 1..128 -> bf16 h[B,E]
__global__ __launch_bounds__(128)
void pool_kernel(const float* __restrict__ X2, bf16* __restrict__ Hout) {
    const int b = blockIdx.x, e = threadIdx.x;
    float acc = 0.f;
    for (int s = 1; s < S_; ++s) acc += X2[((size_t)b * S_ + s) * E_ + e];
    Hout[(size_t)b * E_ + e] = __float2bfloat16(acc * (1.f / 128.f));
}

// ---------------------------------------------------------------------------
extern "C" void kernel_launch(void* const* d_in, const int* in_sizes, int n_in,
                              void* d_out, int out_size, void* d_ws, size_t ws_size,
                              hipStream_t stream) {
    const int* cat_arr      = (const int*)d_in[0];
    const int* dt_arr       = (const int*)d_in[1];
    const int* amount_arr   = (const int*)d_in[2];
    const int* id_arr       = (const int*)d_in[3];
    const float* id_table   = (const float*)d_in[4];
    const float* cat_table  = (const float*)d_in[5];
    const float* amount_tab = (const float*)d_in[6];
    const float* dt_table   = (const float*)d_in[7];
    const float* Wq = (const float*)d_in[8];  const float* bq = (const float*)d_in[9];
    const float* Wk = (const float*)d_in[10]; const float* bk = (const float*)d_in[11];
    const float* Wv = (const float*)d_in[12]; const float* bv = (const float*)d_in[13];
    const float* Wo = (const float*)d_in[14]; const float* bo = (const float*)d_in[15];
    const float* ln1_g = (const float*)d_in[16]; const float* ln1_b = (const float*)d_in[17];
    const float* W1 = (const float*)d_in[18]; const float* b1 = (const float*)d_in[19];
    const float* W2 = (const float*)d_in[20]; const float* b2 = (const float*)d_in[21];
    const float* ln2_g = (const float*)d_in[22]; const float* ln2_b = (const float*)d_in[23];
    const float* lin1_W = (const float*)d_in[24]; const float* lin1_b = (const float*)d_in[25];
    const float* lin2_W = (const float*)d_in[26]; const float* lin2_b = (const float*)d_in[27];
    float* out = (float*)d_out;
    float* ws = (float*)d_ws;

    // Workspace (floats): A | C | D | E | Wd | bias1024  = ~22.6 MiB total
    const size_t ME = (size_t)M_ * E_;           // 2,113,536
    float* X  = ws;                               // slot A: X -> X1 -> X2 (in-place)
    bf16* C0  = (bf16*)(ws + ME);                 // Xb -> Kb -> X1b -> F1b
    bf16* D0  = (bf16*)(ws + ME + ME / 2);        // Qb -> Ob -> hbb/a1b
    bf16* E0  = (bf16*)(ws + 2 * ME);             // Vb
    bf16* Wd  = (bf16*)(ws + 2 * ME + ME / 2);    // 1,277,952 bf16
    float* bias1024 = ws + 2 * ME + ME / 2 + 638976;
    bf16* hbb = D0;                               // [128][128]
    bf16* a1b = D0 + 16384;                       // [128][1024]

    prep_kernel<<<dim3(16, 16, 8), 256, 0, stream>>>(
        Wq, Wk, Wv, Wo, W1, W2, lin1_W, lin2_W, lin1_b, Wd, bias1024);

    embed_kernel<<<M_, 128, 0, stream>>>(cat_arr, dt_arr, amount_arr, id_arr,
                                         id_table, cat_table, amount_tab, dt_table,
                                         X, C0);

    const dim3 gE(M_ / 64, 1);
    // Qb -> D0 ; Vb -> E0 ; Kb -> C0 in-place (LAST: other two still read Xb)
    gemm_mfma<false,false,false,false,true><<<gE, 256, 0, stream>>>(
        C0, Wd, bq, nullptr, nullptr, D0, nullptr, nullptr, 128, 128, 128);
    gemm_mfma<false,false,false,false,true><<<gE, 256, 0, stream>>>(
        C0, Wd + 32768, bv, nullptr, nullptr, E0, nullptr, nullptr, 128, 128, 128);
    gemm_mfma<false,false,false,false,true><<<gE, 256, 0, stream>>>(
        C0, Wd + 16384, bk, nullptr, nullptr, C0, nullptr, nullptr, 128, 128, 128);

    attn_kernel<<<B_ * H_ * 3, 256, 0, stream>>>(D0, C0, E0);   // Ob -> D0

    // X1 = LN1(X + Ob@Wo + bo): f32 in-place X, bf16 X1b -> C0
    gemm_mfma<false,true,true,true,true><<<gE, 256, 0, stream>>>(
        D0, Wd + 49152, bo, X, X, C0, ln1_g, ln1_b, 128, 128, 128);
    // F1b = relu(X1b@W1 + b1) -> C0 in-place
    gemm_mfma<true,false,false,false,true><<<gE, 256, 0, stream>>>(
        C0, Wd + 65536, b1, nullptr, nullptr, C0, nullptr, nullptr, 128, 128, 128);
    // X2 = LN2(X1 + F1b@W2 + b2): f32 in-place X
    gemm_mfma<false,true,true,true,false><<<gE, 256, 0, stream>>>(
        C0, Wd + 81920, b2, X, X, nullptr, ln2_g, ln2_b, 128, 128, 128);

    pool_kernel<<<B_, 128, 0, stream>>>(X, hbb);

    // a1b = relu(hbb@lin1 + b) [128][1024] (pads produce exact zeros)
    gemm_mfma<true,false,false,false,true><<<dim3(2, 8), 256, 0, stream>>>(
        hbb, Wd + 98304, bias1024, nullptr, nullptr, a1b, nullptr, nullptr,
        128, 1024, 1024);
    // out = a1b@lin2 + b  (K=1024 padded, store-guard n<1000)
    gemm_mfma<false,false,false,true,false><<<dim3(2, 8), 256, 0, stream>>>(
        a1b, Wd + 229376, lin2_b, nullptr, out, nullptr, nullptr, nullptr,
        1024, 1000, 1000);
}

// Round 5
// 203.052 us; speedup vs baseline: 1.9771x; 1.2377x over previous
//
#include <hip/hip_runtime.h>
#include <hip/hip_bf16.h>

#define B_ 128
#define L_ 128
#define J_ 64
#define E_ 128
#define H_ 2
#define HD 64
#define S_ 129          // L+1
#define M_ (B_ * S_)    // 16512 tokens
#define CAT_ 1000
#define LN_EPS 1e-5f

typedef __attribute__((ext_vector_type(8))) short bf16x8;
typedef __attribute__((ext_vector_type(4))) float f32x4;
typedef __hip_bfloat16 bf16;

// ---------------------------------------------------------------------------
// prep: transpose+convert all weights to bf16 Bt[N][K]; pad lin1/lin2; pad bias
// Wd bf16 offsets: q=0 k=16384 v=32768 o=49152 w1=65536 w2=81920
//                  lin1=98304 ([1024][128]) lin2=229376 ([1024][1024])
// ---------------------------------------------------------------------------
__global__ __launch_bounds__(256)
void prep_kernel(const float* __restrict__ Wq, const float* __restrict__ Wk,
                 const float* __restrict__ Wv, const float* __restrict__ Wo,
                 const float* __restrict__ W1, const float* __restrict__ W2,
                 const float* __restrict__ lin1W, const float* __restrict__ lin2W,
                 const float* __restrict__ lin1b,
                 bf16* __restrict__ Wd, float* __restrict__ bias1024) {
    const int z = blockIdx.z;
    const float* src; bf16* dst; int Kd, Nd, sK, sN;
    switch (z) {
        case 0: src = Wq;    dst = Wd;          Kd = 128;  Nd = 128;  sK = 128;  sN = 128;  break;
        case 1: src = Wk;    dst = Wd + 16384;  Kd = 128;  Nd = 128;  sK = 128;  sN = 128;  break;
        case 2: src = Wv;    dst = Wd + 32768;  Kd = 128;  Nd = 128;  sK = 128;  sN = 128;  break;
        case 3: src = Wo;    dst = Wd + 49152;  Kd = 128;  Nd = 128;  sK = 128;  sN = 128;  break;
        case 4: src = W1;    dst = Wd + 65536;  Kd = 128;  Nd = 128;  sK = 128;  sN = 128;  break;
        case 5: src = W2;    dst = Wd + 81920;  Kd = 128;  Nd = 128;  sK = 128;  sN = 128;  break;
        case 6: src = lin1W; dst = Wd + 98304;  Kd = 128;  Nd = 1024; sK = 128;  sN = 1000; break;
        default:src = lin2W; dst = Wd + 229376; Kd = 1024; Nd = 1024; sK = 1000; sN = 1000; break;
    }
    if (z == 7 && blockIdx.x == 0 && blockIdx.y == 0) {
        for (int i = threadIdx.x; i < 1024; i += 256)
            bias1024[i] = (i < 1000) ? lin1b[i] : 0.f;
    }
    const int k0 = blockIdx.x * 64, n0 = blockIdx.y * 64;
    if (k0 >= Kd || n0 >= Nd) return;
    __shared__ float t[64][65];
    const int c = threadIdx.x & 63, r0 = threadIdx.x >> 6;
    #pragma unroll 4
    for (int i = 0; i < 16; ++i) {
        const int r = r0 + i * 4;
        const int gk = k0 + r, gn = n0 + c;
        t[r][c] = (gk < sK && gn < sN) ? src[(size_t)gk * sN + gn] : 0.f;
    }
    __syncthreads();
    #pragma unroll 4
    for (int i = 0; i < 16; ++i) {
        const int r = r0 + i * 4;
        dst[(size_t)(n0 + r) * Kd + (k0 + c)] = __float2bfloat16(t[c][r]);
    }
}

// ---------------------------------------------------------------------------
// Embedding: writes f32 X (residual) and bf16 Xb (GEMM A operand)
// ---------------------------------------------------------------------------
__global__ __launch_bounds__(128)
void embed_kernel(const int* __restrict__ cat_arr, const int* __restrict__ dt_arr,
                  const int* __restrict__ amount_arr, const int* __restrict__ id_arr,
                  const float* __restrict__ id_table, const float* __restrict__ cat_table,
                  const float* __restrict__ amount_table, const float* __restrict__ dt_table,
                  float* __restrict__ x, bf16* __restrict__ xb) {
    const int blk = blockIdx.x;
    const int b = blk / S_;
    const int s = blk % S_;
    const int e = threadIdx.x;
    const size_t off = ((size_t)b * S_ + s) * E_ + e;
    if (s == 0) {
        const float v = id_table[(size_t)id_arr[b] * E_ + e];
        x[off] = v; xb[off] = __float2bfloat16(v);
        return;
    }
    const int l = s - 1;
    __shared__ int cs[J_];
    __shared__ int as_[J_];
    if (threadIdx.x < J_) cs[threadIdx.x] = cat_arr[((size_t)b * L_ + l) * J_ + threadIdx.x];
    else as_[threadIdx.x - J_] = amount_arr[((size_t)b * L_ + l) * J_ + threadIdx.x - J_];
    __syncthreads();
    float acc = 0.f;
    #pragma unroll 4
    for (int j = 0; j < J_; ++j) {
        const int c = cs[j];
        if (c != CAT_) {
            acc += cat_table[(size_t)c * E_ + e] + amount_table[(size_t)as_[j] * E_ + e];
        }
    }
    acc += dt_table[(size_t)dt_arr[b * L_ + l] * E_ + e];
    x[off] = acc; xb[off] = __float2bfloat16(acc);
}

// ---------------------------------------------------------------------------
// bf16 MFMA GEMM: C = A[M,K]bf16 @ Bt[N,K]bf16 (+bias)(+resid)(relu|LN)
// BM=64, BN=128, 4 waves x (16 rows x 128 cols). XOR-swizzled LDS.
// SPLITK: gridDim.z parts; f32 partials at Cf + z*M*Nstride, bias skipped.
// ---------------------------------------------------------------------------
template<bool RELU, bool LN, bool HASRES, bool OF32, bool OBF16, bool SPLITK>
__global__ __launch_bounds__(256)
void gemm_mfma(const bf16* __restrict__ A, const bf16* __restrict__ Bt,
               const float* __restrict__ bias, const float* __restrict__ resid,
               float* __restrict__ Cf, bf16* __restrict__ Cb,
               const float* __restrict__ lng, const float* __restrict__ lnb,
               int K, int Nstride, int Nstore) {
    __shared__ bf16x8 Al[64 * 16];    // 16 KiB
    __shared__ bf16x8 Bl[128 * 16];   // 32 KiB
    const int tid = threadIdx.x;
    const int m0 = blockIdx.x * 64;
    const int n0 = blockIdx.y * 128;
    const int w = tid >> 6, l = tid & 63;
    const int l15 = l & 15, g = l >> 4;
    f32x4 acc[8] = {};

    const int z = SPLITK ? blockIdx.z : 0;
    const int ksz = SPLITK ? (K / (int)gridDim.z) : K;
    const int kbeg = z * ksz;

    for (int kc = kbeg; kc < kbeg + ksz; kc += 128) {
        #pragma unroll
        for (int i = 0; i < 4; ++i) {
            const int lin = i * 256 + tid;
            const int r = lin >> 4, u = lin & 15;
            Al[r * 16 + (u ^ (r & 7))] =
                *(const bf16x8*)(A + (size_t)(m0 + r) * K + kc + u * 8);
        }
        #pragma unroll
        for (int i = 0; i < 8; ++i) {
            const int lin = i * 256 + tid;
            const int r = lin >> 4, u = lin & 15;
            Bl[r * 16 + (u ^ (r & 7))] =
                *(const bf16x8*)(Bt + (size_t)(n0 + r) * K + kc + u * 8);
        }
        __syncthreads();
        const int mr = w * 16 + l15;
        #pragma unroll
        for (int s = 0; s < 4; ++s) {
            const int ua = s * 4 + g;
            const bf16x8 a = Al[mr * 16 + (ua ^ (mr & 7))];
            #pragma unroll
            for (int nf = 0; nf < 8; ++nf) {
                const int nr = nf * 16 + l15;
                const bf16x8 b = Bl[nr * 16 + (ua ^ (nr & 7))];
                acc[nf] = __builtin_amdgcn_mfma_f32_16x16x32_bf16(a, b, acc[nf], 0, 0, 0);
            }
        }
        __syncthreads();
    }

    // epilogue: lane l owns rows w*16+g*4+fr, cols nf*16+l15
    #pragma unroll
    for (int fr = 0; fr < 4; ++fr) {
        const int grow = m0 + w * 16 + g * 4 + fr;
        float v[8];
        float s1 = 0.f, s2 = 0.f;
        #pragma unroll
        for (int nf = 0; nf < 8; ++nf) {
            const int col = n0 + nf * 16 + l15;
            float xv = acc[nf][fr];
            if (!SPLITK && col < Nstore) xv += bias[col];
            if (HASRES) xv += resid[(size_t)grow * Nstride + col];
            if (RELU) xv = fmaxf(xv, 0.f);
            v[nf] = xv;
            if (LN) { s1 += xv; s2 += xv * xv; }
        }
        if (LN) {
            #pragma unroll
            for (int off = 1; off < 16; off <<= 1) {
                s1 += __shfl_xor(s1, off);
                s2 += __shfl_xor(s2, off);
            }
            const float mu = s1 * (1.f / 128.f);
            const float rstd = rsqrtf(s2 * (1.f / 128.f) - mu * mu + LN_EPS);
            #pragma unroll
            for (int nf = 0; nf < 8; ++nf) {
                const int col = n0 + nf * 16 + l15;
                v[nf] = (v[nf] - mu) * rstd * lng[col] + lnb[col];
            }
        }
        float* Cfp = SPLITK ? (Cf + (size_t)z * (gridDim.x * 64) * Nstride) : Cf;
        #pragma unroll
        for (int nf = 0; nf < 8; ++nf) {
            const int col = n0 + nf * 16 + l15;
            if (col < Nstore) {
                if (OF32)  Cfp[(size_t)grow * Nstride + col] = v[nf];
                if (OBF16) Cb[(size_t)grow * Nstride + col] = __float2bfloat16(v[nf]);
            }
        }
    }
}

// ---------------------------------------------------------------------------
// MFMA attention: one block per (b,h). Whole-head in LDS.
// Qs/Ks: [144 rows][8 units] bf16x8, XOR-swizzled. Vt: V^T [64][168] bf16.
// Sc: f32 scores [129][132]; P (bf16) written in-place over Sc rows.
// O written in-place into qb (block owns its (b,h) slice).
// ---------------------------------------------------------------------------
__global__ __launch_bounds__(256)
void attn_mfma(bf16* __restrict__ qb, const bf16* __restrict__ kb,
               const bf16* __restrict__ vb) {
    __shared__ __align__(16) bf16x8 Qs[144 * 8];
    __shared__ __align__(16) bf16x8 Ks[144 * 8];
    __shared__ __align__(16) bf16  Vt[64 * 168];
    __shared__ __align__(16) float Sc[129 * 132];
    const int tid = threadIdx.x;
    const int w = tid >> 6, l = tid & 63;
    const int l15 = l & 15, g = l >> 4;
    const int h = blockIdx.x & (H_ - 1);
    const int b = blockIdx.x >> 1;
    const size_t base = ((size_t)b * S_) * E_ + h * HD;

    // stage Q,K: row r, unit u (8 bf16), swizzled u^(r&7)
    for (int idx = tid; idx < S_ * 8; idx += 256) {
        const int r = idx >> 3, u = idx & 7;
        const int us = u ^ (r & 7);
        Qs[r * 8 + us] = *(const bf16x8*)(qb + base + (size_t)r * E_ + u * 8);
        Ks[r * 8 + us] = *(const bf16x8*)(kb + base + (size_t)r * E_ + u * 8);
    }
    // stage V transposed; zero pad t in [129,168)
    for (int idx = tid; idx < 168 * 64; idx += 256) {
        const int t = idx >> 6, d = idx & 63;
        const bf16 val = (t < S_) ? vb[base + (size_t)t * E_ + d]
                                  : __float2bfloat16(0.f);
        Vt[d * 168 + t] = val;
    }
    __syncthreads();

    // QK^T: 81 tiles (9x9 of 16x16), K=64 (2 MFMA each)
    for (int i = w; i < 81; i += 4) {
        const int rt = i / 9, ct = i - rt * 9;
        const int qr = rt * 16 + l15;          // < 144, in-bounds
        const int kr = ct * 16 + l15;
        f32x4 acc = {};
        #pragma unroll
        for (int s = 0; s < 2; ++s) {
            const int ua = s * 4 + g;
            acc = __builtin_amdgcn_mfma_f32_16x16x32_bf16(
                Qs[qr * 8 + (ua ^ (qr & 7))], Ks[kr * 8 + (ua ^ (kr & 7))],
                acc, 0, 0, 0);
        }
        const int col = ct * 16 + l15;
        #pragma unroll
        for (int r = 0; r < 4; ++r) {
            const int row = rt * 16 + g * 4 + r;
            // col<132 guard: ct=8 writes cols 128..143; cols >=132 would
            // overflow the row stride and corrupt the next row's cols 0..11.
            if (row < S_ && col < 132) Sc[row * 132 + col] = acc[r] * 0.125f;
        }
    }
    __syncthreads();

    // wave-parallel softmax; write bf16 P in-place over each Sc row
    for (int r = w; r < S_; r += 4) {
        float* Srow = Sc + r * 132;
        const float e0 = Srow[l];
        const float e1 = Srow[l + 64];
        const float e2 = (l == 0) ? Srow[128] : -1e30f;
        float m = fmaxf(fmaxf(e0, e1), e2);
        #pragma unroll
        for (int off = 1; off < 64; off <<= 1) m = fmaxf(m, __shfl_xor(m, off));
        const float p0 = __expf(e0 - m);
        const float p1 = __expf(e1 - m);
        const float p2 = (l == 0) ? __expf(e2 - m) : 0.f;
        float s = p0 + p1 + p2;
        #pragma unroll
        for (int off = 1; off < 64; off <<= 1) s += __shfl_xor(s, off);
        const float inv = 1.f / s;
        bf16* Prow = (bf16*)Srow;
        Prow[l] = __float2bfloat16(p0 * inv);
        Prow[l + 64] = __float2bfloat16(p1 * inv);
        if (l == 0) Prow[128] = __float2bfloat16(p2 * inv);
        if (l < 31) Prow[129 + l] = __float2bfloat16(0.f);   // zero k-pad 129..159
    }
    __syncthreads();

    // PV: O[129][64] = P[129][160] @ V[160][64]; 36 tiles x 5 k-chunks
    for (int i = w; i < 36; i += 4) {
        const int rt = i >> 2, ct = i & 3;
        int pr = rt * 16 + l15; if (pr > 128) pr = 128;   // clamp: rows >=129 unstored
        const bf16* Prow = (const bf16*)(Sc + pr * 132);
        const bf16* Vrow = Vt + (ct * 16 + l15) * 168;
        f32x4 acc = {};
        #pragma unroll
        for (int kc = 0; kc < 5; ++kc) {
            const bf16x8 a = *(const bf16x8*)(Prow + kc * 32 + g * 8);
            const bf16x8 bb = *(const bf16x8*)(Vrow + kc * 32 + g * 8);
            acc = __builtin_amdgcn_mfma_f32_16x16x32_bf16(a, bb, acc, 0, 0, 0);
        }
        #pragma unroll
        for (int r = 0; r < 4; ++r) {
            const int orow = rt * 16 + g * 4 + r;
            if (orow < S_)
                qb[base + (size_t)orow * E_ + ct * 16 + l15] =
                    __float2bfloat16(acc[r]);
        }
    }
}

// mean-pool tokens 1..128 -> bf16 h[B,E]
__global__ __launch_bounds__(128)
void pool_kernel(const float* __restrict__ X2, bf16* __restrict__ Hout) {
    const int b = blockIdx.x, e = threadIdx.x;
    float acc = 0.f;
    for (int s = 1; s < S_; ++s) acc += X2[((size_t)b * S_ + s) * E_ + e];
    Hout[(size_t)b * E_ + e] = __float2bfloat16(acc * (1.f / 128.f));
}

// reduce split-K partials [4][128][1024] -> out[128][1000] (+bias)
__global__ __launch_bounds__(256)
void splitk_reduce(const float* __restrict__ part, const float* __restrict__ bias,
                   float* __restrict__ out) {
    const int i = blockIdx.x * 256 + threadIdx.x;
    if (i >= B_ * CAT_) return;
    const int m = i / CAT_, n = i - m * CAT_;
    float v = bias[n];
    #pragma unroll
    for (int z = 0; z < 4; ++z) v += part[(size_t)z * 131072 + m * 1024 + n];
    out[i] = v;
}

// ---------------------------------------------------------------------------
extern "C" void kernel_launch(void* const* d_in, const int* in_sizes, int n_in,
                              void* d_out, int out_size, void* d_ws, size_t ws_size,
                              hipStream_t stream) {
    const int* cat_arr      = (const int*)d_in[0];
    const int* dt_arr       = (const int*)d_in[1];
    const int* amount_arr   = (const int*)d_in[2];
    const int* id_arr       = (const int*)d_in[3];
    const float* id_table   = (const float*)d_in[4];
    const float* cat_table  = (const float*)d_in[5];
    const float* amount_tab = (const float*)d_in[6];
    const float* dt_table   = (const float*)d_in[7];
    const float* Wq = (const float*)d_in[8];  const float* bq = (const float*)d_in[9];
    const float* Wk = (const float*)d_in[10]; const float* bk = (const float*)d_in[11];
    const float* Wv = (const float*)d_in[12]; const float* bv = (const float*)d_in[13];
    const float* Wo = (const float*)d_in[14]; const float* bo = (const float*)d_in[15];
    const float* ln1_g = (const float*)d_in[16]; const float* ln1_b = (const float*)d_in[17];
    const float* W1 = (const float*)d_in[18]; const float* b1 = (const float*)d_in[19];
    const float* W2 = (const float*)d_in[20]; const float* b2 = (const float*)d_in[21];
    const float* ln2_g = (const float*)d_in[22]; const float* ln2_b = (const float*)d_in[23];
    const float* lin1_W = (const float*)d_in[24]; const float* lin1_b = (const float*)d_in[25];
    const float* lin2_W = (const float*)d_in[26]; const float* lin2_b = (const float*)d_in[27];
    float* out = (float*)d_out;
    float* ws = (float*)d_ws;

    // Workspace (floats), total ~23.7 MiB:
    //   X[ME] | C0 bf16[ME] | D0 bf16[ME] | E0 bf16[ME] | Wd bf16 | bias1024
    const size_t ME = (size_t)M_ * E_;           // 2,113,536
    float* X  = ws;                               // f32 x -> x1 -> x2 (in-place)
    bf16* C0  = (bf16*)(ws + ME);                 // Xb -> Kb -> X1b -> F1b
    bf16* D0  = (bf16*)(ws + ME + ME / 2);        // Qb -> Ob -> hbb/a1b
    bf16* E0  = (bf16*)(ws + 2 * ME);             // Vb -> (f32 prt)
    bf16* Wd  = (bf16*)(ws + 2 * ME + ME / 2);    // 1,277,952 bf16
    float* bias1024 = ws + 2 * ME + ME / 2 + 638976;
    bf16* hbb = D0;                               // [128][128]
    bf16* a1b = D0 + 16384;                       // [128][1024]
    float* prt = (float*)E0;                      // [4][128][1024] f32 (2 MiB)

    prep_kernel<<<dim3(16, 16, 8), 256, 0, stream>>>(
        Wq, Wk, Wv, Wo, W1, W2, lin1_W, lin2_W, lin1_b, Wd, bias1024);

    embed_kernel<<<M_, 128, 0, stream>>>(cat_arr, dt_arr, amount_arr, id_arr,
                                         id_table, cat_table, amount_tab, dt_table,
                                         X, C0);

    const dim3 gE(M_ / 64, 1);
    // Qb -> D0 ; Vb -> E0 ; Kb -> C0 in-place (LAST: other two still read Xb)
    gemm_mfma<false,false,false,false,true,false><<<gE, 256, 0, stream>>>(
        C0, Wd, bq, nullptr, nullptr, D0, nullptr, nullptr, 128, 128, 128);
    gemm_mfma<false,false,false,false,true,false><<<gE, 256, 0, stream>>>(
        C0, Wd + 32768, bv, nullptr, nullptr, E0, nullptr, nullptr, 128, 128, 128);
    gemm_mfma<false,false,false,false,true,false><<<gE, 256, 0, stream>>>(
        C0, Wd + 16384, bk, nullptr, nullptr, C0, nullptr, nullptr, 128, 128, 128);

    attn_mfma<<<B_ * H_, 256, 0, stream>>>(D0, C0, E0);       // Ob -> D0

    // X1 = LN1(X + Ob@Wo + bo): f32 in-place X, bf16 X1b -> C0
    gemm_mfma<false,true,true,true,true,false><<<gE, 256, 0, stream>>>(
        D0, Wd + 49152, bo, X, X, C0, ln1_g, ln1_b, 128, 128, 128);
    // F1b = relu(X1b@W1 + b1) -> C0 in-place
    gemm_mfma<true,false,false,false,true,false><<<gE, 256, 0, stream>>>(
        C0, Wd + 65536, b1, nullptr, nullptr, C0, nullptr, nullptr, 128, 128, 128);
    // X2 = LN2(X1 + F1b@W2 + b2): f32 in-place X
    gemm_mfma<false,true,true,true,false,false><<<gE, 256, 0, stream>>>(
        C0, Wd + 81920, b2, X, X, nullptr, ln2_g, ln2_b, 128, 128, 128);

    pool_kernel<<<B_, 128, 0, stream>>>(X, hbb);

    // a1b = relu(hbb@lin1 + b) [128][1024]
    gemm_mfma<true,false,false,false,true,false><<<dim3(2, 8), 256, 0, stream>>>(
        hbb, Wd + 98304, bias1024, nullptr, nullptr, a1b, nullptr, nullptr,
        128, 1024, 1024);
    // prt[z] = a1b@lin2 partials (K=1024 split 4 ways)
    gemm_mfma<false,false,false,true,false,true><<<dim3(2, 8, 4), 256, 0, stream>>>(
        a1b, Wd + 229376, nullptr, nullptr, prt, nullptr, nullptr, nullptr,
        1024, 1024, 1024);
    splitk_reduce<<<(B_ * CAT_ + 255) / 256, 256, 0, stream>>>(prt, lin2_b, out);
}

// Round 6
// 183.244 us; speedup vs baseline: 2.1909x; 1.1081x over previous
//
#include <hip/hip_runtime.h>
#include <hip/hip_bf16.h>

#define B_ 128
#define L_ 128
#define J_ 64
#define E_ 128
#define H_ 2
#define HD 64
#define S_ 129          // L+1
#define M_ (B_ * S_)    // 16512 tokens
#define CAT_ 1000
#define LN_EPS 1e-5f

typedef __attribute__((ext_vector_type(8))) short bf16x8;
typedef __attribute__((ext_vector_type(4))) float f32x4;
typedef __hip_bfloat16 bf16;

__device__ inline float bf2f(unsigned short u) {
    union { unsigned int i; float f; } v; v.i = (unsigned int)u << 16; return v.f;
}
__device__ inline unsigned short f2bu(float f) {
    __hip_bfloat16 h = __float2bfloat16(f);
    return *reinterpret_cast<unsigned short*>(&h);
}

// ---------------------------------------------------------------------------
// prep: transpose+convert weights to bf16 Bt[N][K]; pad lin1/lin2; pad bias;
// z=8/9: convert cat/amount tables to bf16 (row-layout unchanged).
// Wd bf16 offsets: q=0 k=16384 v=32768 o=49152 w1=65536 w2=81920
//                  lin1=98304 ([1024][128]) lin2=229376 ([1024][1024])
// ---------------------------------------------------------------------------
__global__ __launch_bounds__(256)
void prep_kernel(const float* __restrict__ Wq, const float* __restrict__ Wk,
                 const float* __restrict__ Wv, const float* __restrict__ Wo,
                 const float* __restrict__ W1, const float* __restrict__ W2,
                 const float* __restrict__ lin1W, const float* __restrict__ lin2W,
                 const float* __restrict__ lin1b,
                 const float* __restrict__ cat_table, const float* __restrict__ amount_table,
                 bf16* __restrict__ Wd, float* __restrict__ bias1024,
                 bf16* __restrict__ catb, bf16* __restrict__ amtb) {
    const int z = blockIdx.z;
    const int tid = threadIdx.x;
    if (z == 8) {   // cat_table -> bf16, 128000 elems
        const int gid = (blockIdx.x * 16 + blockIdx.y) * 256 + tid;
        for (int i = gid; i < 1000 * 128; i += 65536)
            catb[i] = __float2bfloat16(cat_table[i]);
        return;
    }
    if (z == 9) {   // amount_table -> bf16, 12800 elems
        const int gid = (blockIdx.x * 16 + blockIdx.y) * 256 + tid;
        for (int i = gid; i < 100 * 128; i += 65536)
            amtb[i] = __float2bfloat16(amount_table[i]);
        return;
    }
    const float* src; bf16* dst; int Kd, Nd, sK, sN;
    switch (z) {
        case 0: src = Wq;    dst = Wd;          Kd = 128;  Nd = 128;  sK = 128;  sN = 128;  break;
        case 1: src = Wk;    dst = Wd + 16384;  Kd = 128;  Nd = 128;  sK = 128;  sN = 128;  break;
        case 2: src = Wv;    dst = Wd + 32768;  Kd = 128;  Nd = 128;  sK = 128;  sN = 128;  break;
        case 3: src = Wo;    dst = Wd + 49152;  Kd = 128;  Nd = 128;  sK = 128;  sN = 128;  break;
        case 4: src = W1;    dst = Wd + 65536;  Kd = 128;  Nd = 128;  sK = 128;  sN = 128;  break;
        case 5: src = W2;    dst = Wd + 81920;  Kd = 128;  Nd = 128;  sK = 128;  sN = 128;  break;
        case 6: src = lin1W; dst = Wd + 98304;  Kd = 128;  Nd = 1024; sK = 128;  sN = 1000; break;
        default:src = lin2W; dst = Wd + 229376; Kd = 1024; Nd = 1024; sK = 1000; sN = 1000; break;
    }
    if (z == 7 && blockIdx.x == 0 && blockIdx.y == 0) {
        for (int i = tid; i < 1024; i += 256)
            bias1024[i] = (i < 1000) ? lin1b[i] : 0.f;
    }
    const int k0 = blockIdx.x * 64, n0 = blockIdx.y * 64;
    if (k0 >= Kd || n0 >= Nd) return;
    __shared__ float t[64][65];
    const int c = tid & 63, r0 = tid >> 6;
    #pragma unroll 4
    for (int i = 0; i < 16; ++i) {
        const int r = r0 + i * 4;
        const int gk = k0 + r, gn = n0 + c;
        t[r][c] = (gk < sK && gn < sN) ? src[(size_t)gk * sN + gn] : 0.f;
    }
    __syncthreads();
    #pragma unroll 4
    for (int i = 0; i < 16; ++i) {
        const int r = r0 + i * 4;
        dst[(size_t)(n0 + r) * Kd + (k0 + c)] = __float2bfloat16(t[c][r]);
    }
}

// ---------------------------------------------------------------------------
// Embedding v2: 8 tokens/block, 32 lanes/token, 4 elems/lane (vectorized).
// bf16 tables (catb/amtb), f32 dt/id. Writes f32 X and bf16 Xb.
// ---------------------------------------------------------------------------
__global__ __launch_bounds__(256)
void embed_kernel(const int* __restrict__ cat_arr, const int* __restrict__ dt_arr,
                  const int* __restrict__ amount_arr, const int* __restrict__ id_arr,
                  const float* __restrict__ id_table, const bf16* __restrict__ catb,
                  const bf16* __restrict__ amtb, const float* __restrict__ dt_table,
                  float* __restrict__ x, bf16* __restrict__ xb) {
    __shared__ int cs[8][64];
    __shared__ int as_[8][64];
    const int tid = threadIdx.x;
    const int g = tid >> 5, lg = tid & 31;
    const int t = blockIdx.x * 8 + g;
    const int b = t / S_, s = t - b * S_;
    if (s > 0) {
        const int base = (b * L_ + (s - 1)) * J_;
        cs[g][lg]       = cat_arr[base + lg];
        cs[g][lg + 32]  = cat_arr[base + lg + 32];
        as_[g][lg]      = amount_arr[base + lg];
        as_[g][lg + 32] = amount_arr[base + lg + 32];
    }
    __syncthreads();
    const size_t off = (size_t)t * E_ + lg * 4;
    float a0, a1, a2, a3;
    if (s == 0) {
        const float4 v = *(const float4*)(id_table + (size_t)id_arr[b] * E_ + lg * 4);
        a0 = v.x; a1 = v.y; a2 = v.z; a3 = v.w;
    } else {
        a0 = a1 = a2 = a3 = 0.f;
        #pragma unroll 4
        for (int j = 0; j < J_; ++j) {
            const int c = cs[g][j];
            if (c != CAT_) {
                const ushort4 cu = *(const ushort4*)(catb + (size_t)c * E_ + lg * 4);
                const ushort4 au = *(const ushort4*)(amtb + (size_t)as_[g][j] * E_ + lg * 4);
                a0 += bf2f(cu.x) + bf2f(au.x);
                a1 += bf2f(cu.y) + bf2f(au.y);
                a2 += bf2f(cu.z) + bf2f(au.z);
                a3 += bf2f(cu.w) + bf2f(au.w);
            }
        }
        const float4 dv = *(const float4*)(dt_table + (size_t)dt_arr[b * L_ + s - 1] * E_ + lg * 4);
        a0 += dv.x; a1 += dv.y; a2 += dv.z; a3 += dv.w;
    }
    float4 xo; xo.x = a0; xo.y = a1; xo.z = a2; xo.w = a3;
    *(float4*)(x + off) = xo;
    ushort4 bo; bo.x = f2bu(a0); bo.y = f2bu(a1); bo.z = f2bu(a2); bo.w = f2bu(a3);
    *(ushort4*)(xb + off) = bo;
}

// ---------------------------------------------------------------------------
// bf16 MFMA GEMM: C = A[M,K]bf16 @ Bt[N,K]bf16 (+bias)(+resid)(relu|LN)
// BM=64, BN=128, 4 waves x (16 rows x 128 cols). XOR-swizzled LDS.
// SPLITK: gridDim.z parts; f32 partials at Cf + z*M*Nstride, bias skipped.
// ---------------------------------------------------------------------------
template<bool RELU, bool LN, bool HASRES, bool OF32, bool OBF16, bool SPLITK>
__global__ __launch_bounds__(256)
void gemm_mfma(const bf16* __restrict__ A, const bf16* __restrict__ Bt,
               const float* __restrict__ bias, const float* __restrict__ resid,
               float* __restrict__ Cf, bf16* __restrict__ Cb,
               const float* __restrict__ lng, const float* __restrict__ lnb,
               int K, int Nstride, int Nstore) {
    __shared__ bf16x8 Al[64 * 16];    // 16 KiB
    __shared__ bf16x8 Bl[128 * 16];   // 32 KiB
    const int tid = threadIdx.x;
    const int m0 = blockIdx.x * 64;
    const int n0 = blockIdx.y * 128;
    const int w = tid >> 6, l = tid & 63;
    const int l15 = l & 15, g = l >> 4;
    f32x4 acc[8] = {};

    const int z = SPLITK ? blockIdx.z : 0;
    const int ksz = SPLITK ? (K / (int)gridDim.z) : K;
    const int kbeg = z * ksz;

    for (int kc = kbeg; kc < kbeg + ksz; kc += 128) {
        #pragma unroll
        for (int i = 0; i < 4; ++i) {
            const int lin = i * 256 + tid;
            const int r = lin >> 4, u = lin & 15;
            Al[r * 16 + (u ^ (r & 7))] =
                *(const bf16x8*)(A + (size_t)(m0 + r) * K + kc + u * 8);
        }
        #pragma unroll
        for (int i = 0; i < 8; ++i) {
            const int lin = i * 256 + tid;
            const int r = lin >> 4, u = lin & 15;
            Bl[r * 16 + (u ^ (r & 7))] =
                *(const bf16x8*)(Bt + (size_t)(n0 + r) * K + kc + u * 8);
        }
        __syncthreads();
        const int mr = w * 16 + l15;
        #pragma unroll
        for (int s = 0; s < 4; ++s) {
            const int ua = s * 4 + g;
            const bf16x8 a = Al[mr * 16 + (ua ^ (mr & 7))];
            #pragma unroll
            for (int nf = 0; nf < 8; ++nf) {
                const int nr = nf * 16 + l15;
                const bf16x8 b = Bl[nr * 16 + (ua ^ (nr & 7))];
                acc[nf] = __builtin_amdgcn_mfma_f32_16x16x32_bf16(a, b, acc[nf], 0, 0, 0);
            }
        }
        __syncthreads();
    }

    // epilogue: lane l owns rows w*16+g*4+fr, cols nf*16+l15
    #pragma unroll
    for (int fr = 0; fr < 4; ++fr) {
        const int grow = m0 + w * 16 + g * 4 + fr;
        float v[8];
        float s1 = 0.f, s2 = 0.f;
        #pragma unroll
        for (int nf = 0; nf < 8; ++nf) {
            const int col = n0 + nf * 16 + l15;
            float xv = acc[nf][fr];
            if (!SPLITK && col < Nstore) xv += bias[col];
            if (HASRES) xv += resid[(size_t)grow * Nstride + col];
            if (RELU) xv = fmaxf(xv, 0.f);
            v[nf] = xv;
            if (LN) { s1 += xv; s2 += xv * xv; }
        }
        if (LN) {
            #pragma unroll
            for (int off = 1; off < 16; off <<= 1) {
                s1 += __shfl_xor(s1, off);
                s2 += __shfl_xor(s2, off);
            }
            const float mu = s1 * (1.f / 128.f);
            const float rstd = rsqrtf(s2 * (1.f / 128.f) - mu * mu + LN_EPS);
            #pragma unroll
            for (int nf = 0; nf < 8; ++nf) {
                const int col = n0 + nf * 16 + l15;
                v[nf] = (v[nf] - mu) * rstd * lng[col] + lnb[col];
            }
        }
        float* Cfp = SPLITK ? (Cf + (size_t)z * (gridDim.x * 64) * Nstride) : Cf;
        #pragma unroll
        for (int nf = 0; nf < 8; ++nf) {
            const int col = n0 + nf * 16 + l15;
            if (col < Nstore) {
                if (OF32)  Cfp[(size_t)grow * Nstride + col] = v[nf];
                if (OBF16) Cb[(size_t)grow * Nstride + col] = __float2bfloat16(v[nf]);
            }
        }
    }
}

// ---------------------------------------------------------------------------
// MFMA attention: one block per (b,h). Whole-head in LDS.
// Qs/Ks: [144 rows][8 units] bf16x8, XOR-swizzled. Vt: V^T [64][168] bf16.
// Sc: f32 scores [129][132]; P (bf16) written in-place over Sc rows.
// O written in-place into qb (block owns its (b,h) slice).
// ---------------------------------------------------------------------------
__global__ __launch_bounds__(256)
void attn_mfma(bf16* __restrict__ qb, const bf16* __restrict__ kb,
               const bf16* __restrict__ vb) {
    __shared__ __align__(16) bf16x8 Qs[144 * 8];
    __shared__ __align__(16) bf16x8 Ks[144 * 8];
    __shared__ __align__(16) bf16  Vt[64 * 168];
    __shared__ __align__(16) float Sc[129 * 132];
    const int tid = threadIdx.x;
    const int w = tid >> 6, l = tid & 63;
    const int l15 = l & 15, g = l >> 4;
    const int h = blockIdx.x & (H_ - 1);
    const int b = blockIdx.x >> 1;
    const size_t base = ((size_t)b * S_) * E_ + h * HD;

    // stage Q,K: row r, unit u (8 bf16), swizzled u^(r&7)
    for (int idx = tid; idx < S_ * 8; idx += 256) {
        const int r = idx >> 3, u = idx & 7;
        const int us = u ^ (r & 7);
        Qs[r * 8 + us] = *(const bf16x8*)(qb + base + (size_t)r * E_ + u * 8);
        Ks[r * 8 + us] = *(const bf16x8*)(kb + base + (size_t)r * E_ + u * 8);
    }
    // stage V transposed; zero pad t in [129,168)
    for (int idx = tid; idx < 168 * 64; idx += 256) {
        const int t = idx >> 6, d = idx & 63;
        const bf16 val = (t < S_) ? vb[base + (size_t)t * E_ + d]
                                  : __float2bfloat16(0.f);
        Vt[d * 168 + t] = val;
    }
    __syncthreads();

    // QK^T: 81 tiles (9x9 of 16x16), K=64 (2 MFMA each)
    for (int i = w; i < 81; i += 4) {
        const int rt = i / 9, ct = i - rt * 9;
        const int qr = rt * 16 + l15;          // < 144, in-bounds
        const int kr = ct * 16 + l15;
        f32x4 acc = {};
        #pragma unroll
        for (int s = 0; s < 2; ++s) {
            const int ua = s * 4 + g;
            acc = __builtin_amdgcn_mfma_f32_16x16x32_bf16(
                Qs[qr * 8 + (ua ^ (qr & 7))], Ks[kr * 8 + (ua ^ (kr & 7))],
                acc, 0, 0, 0);
        }
        const int col = ct * 16 + l15;
        #pragma unroll
        for (int r = 0; r < 4; ++r) {
            const int row = rt * 16 + g * 4 + r;
            // col<132 guard: ct=8 writes cols 128..143; cols >=132 would
            // overflow the row stride and corrupt the next row's cols 0..11.
            if (row < S_ && col < 132) Sc[row * 132 + col] = acc[r] * 0.125f;
        }
    }
    __syncthreads();

    // wave-parallel softmax; write bf16 P in-place over each Sc row
    for (int r = w; r < S_; r += 4) {
        float* Srow = Sc + r * 132;
        const float e0 = Srow[l];
        const float e1 = Srow[l + 64];
        const float e2 = (l == 0) ? Srow[128] : -1e30f;
        float m = fmaxf(fmaxf(e0, e1), e2);
        #pragma unroll
        for (int off = 1; off < 64; off <<= 1) m = fmaxf(m, __shfl_xor(m, off));
        const float p0 = __expf(e0 - m);
        const float p1 = __expf(e1 - m);
        const float p2 = (l == 0) ? __expf(e2 - m) : 0.f;
        float s = p0 + p1 + p2;
        #pragma unroll
        for (int off = 1; off < 64; off <<= 1) s += __shfl_xor(s, off);
        const float inv = 1.f / s;
        bf16* Prow = (bf16*)Srow;
        Prow[l] = __float2bfloat16(p0 * inv);
        Prow[l + 64] = __float2bfloat16(p1 * inv);
        if (l == 0) Prow[128] = __float2bfloat16(p2 * inv);
        if (l < 31) Prow[129 + l] = __float2bfloat16(0.f);   // zero k-pad 129..159
    }
    __syncthreads();

    // PV: O[129][64] = P[129][160] @ V[160][64]; 36 tiles x 5 k-chunks
    for (int i = w; i < 36; i += 4) {
        const int rt = i >> 2, ct = i & 3;
        int pr = rt * 16 + l15; if (pr > 128) pr = 128;   // clamp: rows >=129 unstored
        const bf16* Prow = (const bf16*)(Sc + pr * 132);
        const bf16* Vrow = Vt + (ct * 16 + l15) * 168;
        f32x4 acc = {};
        #pragma unroll
        for (int kc = 0; kc < 5; ++kc) {
            const bf16x8 a = *(const bf16x8*)(Prow + kc * 32 + g * 8);
            const bf16x8 bb = *(const bf16x8*)(Vrow + kc * 32 + g * 8);
            acc = __builtin_amdgcn_mfma_f32_16x16x32_bf16(a, bb, acc, 0, 0, 0);
        }
        #pragma unroll
        for (int r = 0; r < 4; ++r) {
            const int orow = rt * 16 + g * 4 + r;
            if (orow < S_)
                qb[base + (size_t)orow * E_ + ct * 16 + l15] =
                    __float2bfloat16(acc[r]);
        }
    }
}

// mean-pool tokens 1..128 -> bf16 h[B,E]
__global__ __launch_bounds__(128)
void pool_kernel(const float* __restrict__ X2, bf16* __restrict__ Hout) {
    const int b = blockIdx.x, e = threadIdx.x;
    float acc = 0.f;
    for (int s = 1; s < S_; ++s) acc += X2[((size_t)b * S_ + s) * E_ + e];
    Hout[(size_t)b * E_ + e] = __float2bfloat16(acc * (1.f / 128.f));
}

// reduce split-K partials [4][128][1024] -> out[128][1000] (+bias)
__global__ __launch_bounds__(256)
void splitk_reduce(const float* __restrict__ part, const float* __restrict__ bias,
                   float* __restrict__ out) {
    const int i = blockIdx.x * 256 + threadIdx.x;
    if (i >= B_ * CAT_) return;
    const int m = i / CAT_, n = i - m * CAT_;
    float v = bias[n];
    #pragma unroll
    for (int z = 0; z < 4; ++z) v += part[(size_t)z * 131072 + m * 1024 + n];
    out[i] = v;
}

// ---------------------------------------------------------------------------
extern "C" void kernel_launch(void* const* d_in, const int* in_sizes, int n_in,
                              void* d_out, int out_size, void* d_ws, size_t ws_size,
                              hipStream_t stream) {
    const int* cat_arr      = (const int*)d_in[0];
    const int* dt_arr       = (const int*)d_in[1];
    const int* amount_arr   = (const int*)d_in[2];
    const int* id_arr       = (const int*)d_in[3];
    const float* id_table   = (const float*)d_in[4];
    const float* cat_table  = (const float*)d_in[5];
    const float* amount_tab = (const float*)d_in[6];
    const float* dt_table   = (const float*)d_in[7];
    const float* Wq = (const float*)d_in[8];  const float* bq = (const float*)d_in[9];
    const float* Wk = (const float*)d_in[10]; const float* bk = (const float*)d_in[11];
    const float* Wv = (const float*)d_in[12]; const float* bv = (const float*)d_in[13];
    const float* Wo = (const float*)d_in[14]; const float* bo = (const float*)d_in[15];
    const float* ln1_g = (const float*)d_in[16]; const float* ln1_b = (const float*)d_in[17];
    const float* W1 = (const float*)d_in[18]; const float* b1 = (const float*)d_in[19];
    const float* W2 = (const float*)d_in[20]; const float* b2 = (const float*)d_in[21];
    const float* ln2_g = (const float*)d_in[22]; const float* ln2_b = (const float*)d_in[23];
    const float* lin1_W = (const float*)d_in[24]; const float* lin1_b = (const float*)d_in[25];
    const float* lin2_W = (const float*)d_in[26]; const float* lin2_b = (const float*)d_in[27];
    float* out = (float*)d_out;
    float* ws = (float*)d_ws;

    // Workspace (floats), total ~22.9 MiB:
    //   X[ME] | C0 bf16[ME] | D0 bf16[ME] | E0 bf16[ME] | Wd | bias1024 | catb | amtb
    const size_t ME = (size_t)M_ * E_;           // 2,113,536
    float* X  = ws;                               // f32 x -> x1 -> x2 (in-place)
    bf16* C0  = (bf16*)(ws + ME);                 // Xb -> Kb -> X1b -> F1b
    bf16* D0  = (bf16*)(ws + ME + ME / 2);        // Qb -> Ob -> hbb/a1b
    bf16* E0  = (bf16*)(ws + 2 * ME);             // Vb -> (f32 prt)
    bf16* Wd  = (bf16*)(ws + 2 * ME + ME / 2);    // 1,277,952 bf16
    float* bias1024 = ws + 2 * ME + ME / 2 + 638976;
    bf16* catb = (bf16*)(bias1024 + 1024);        // [1000][128] bf16
    bf16* amtb = catb + 128000;                   // [100][128] bf16
    bf16* hbb = D0;                               // [128][128]
    bf16* a1b = D0 + 16384;                       // [128][1024]
    float* prt = (float*)E0;                      // [4][128][1024] f32 (2 MiB)

    prep_kernel<<<dim3(16, 16, 10), 256, 0, stream>>>(
        Wq, Wk, Wv, Wo, W1, W2, lin1_W, lin2_W, lin1_b,
        cat_table, amount_tab, Wd, bias1024, catb, amtb);

    embed_kernel<<<M_ / 8, 256, 0, stream>>>(cat_arr, dt_arr, amount_arr, id_arr,
                                             id_table, catb, amtb, dt_table,
                                             X, C0);

    const dim3 gE(M_ / 64, 1);
    // Qb -> D0 ; Vb -> E0 ; Kb -> C0 in-place (LAST: other two still read Xb)
    gemm_mfma<false,false,false,false,true,false><<<gE, 256, 0, stream>>>(
        C0, Wd, bq, nullptr, nullptr, D0, nullptr, nullptr, 128, 128, 128);
    gemm_mfma<false,false,false,false,true,false><<<gE, 256, 0, stream>>>(
        C0, Wd + 32768, bv, nullptr, nullptr, E0, nullptr, nullptr, 128, 128, 128);
    gemm_mfma<false,false,false,false,true,false><<<gE, 256, 0, stream>>>(
        C0, Wd + 16384, bk, nullptr, nullptr, C0, nullptr, nullptr, 128, 128, 128);

    attn_mfma<<<B_ * H_, 256, 0, stream>>>(D0, C0, E0);       // Ob -> D0

    // X1 = LN1(X + Ob@Wo + bo): f32 in-place X, bf16 X1b -> C0
    gemm_mfma<false,true,true,true,true,false><<<gE, 256, 0, stream>>>(
        D0, Wd + 49152, bo, X, X, C0, ln1_g, ln1_b, 128, 128, 128);
    // F1b = relu(X1b@W1 + b1) -> C0 in-place
    gemm_mfma<true,false,false,false,true,false><<<gE, 256, 0, stream>>>(
        C0, Wd + 65536, b1, nullptr, nullptr, C0, nullptr, nullptr, 128, 128, 128);
    // X2 = LN2(X1 + F1b@W2 + b2): f32 in-place X
    gemm_mfma<false,true,true,true,false,false><<<gE, 256, 0, stream>>>(
        C0, Wd + 81920, b2, X, X, nullptr, ln2_g, ln2_b, 128, 128, 128);

    pool_kernel<<<B_, 128, 0, stream>>>(X, hbb);

    // a1b = relu(hbb@lin1 + b) [128][1024]
    gemm_mfma<true,false,false,false,true,false><<<dim3(2, 8), 256, 0, stream>>>(
        hbb, Wd + 98304, bias1024, nullptr, nullptr, a1b, nullptr, nullptr,
        128, 1024, 1024);
    // prt[z] = a1b@lin2 partials (K=1024 split 4 ways)
    gemm_mfma<false,false,false,true,false,true><<<dim3(2, 8, 4), 256, 0, stream>>>(
        a1b, Wd + 229376, nullptr, nullptr, prt, nullptr, nullptr, nullptr,
        1024, 1024, 1024);
    splitk_reduce<<<(B_ * CAT_ + 255) / 256, 256, 0, stream>>>(prt, lin2_b, out);
}

// Round 7
// 168.142 us; speedup vs baseline: 2.3876x; 1.0898x over previous
//
#include <hip/hip_runtime.h>
#include <hip/hip_bf16.h>

#define B_ 128
#define L_ 128
#define J_ 64
#define E_ 128
#define H_ 2
#define HD 64
#define S_ 129          // L+1
#define M_ (B_ * S_)    // 16512 tokens
#define CAT_ 1000
#define LN_EPS 1e-5f

typedef __attribute__((ext_vector_type(8))) short bf16x8;
typedef __attribute__((ext_vector_type(4))) float f32x4;
typedef __hip_bfloat16 bf16;

__device__ inline float bf2f(unsigned short u) {
    union { unsigned int i; float f; } v; v.i = (unsigned int)u << 16; return v.f;
}
__device__ inline unsigned short f2bu(float f) {
    __hip_bfloat16 h = __float2bfloat16(f);
    return *reinterpret_cast<unsigned short*>(&h);
}

// ---------------------------------------------------------------------------
// prep: transpose+convert weights to bf16 Bt[N][K]; pad lin1/lin2; pad bias;
// z=8/9: convert cat/amount tables to bf16 (row-layout unchanged).
// Wd bf16 offsets: q=0 k=16384 v=32768 o=49152 w1=65536 w2=81920
//                  lin1=98304 ([1024][128]) lin2=229376 ([1024][1024])
// ---------------------------------------------------------------------------
__global__ __launch_bounds__(256)
void prep_kernel(const float* __restrict__ Wq, const float* __restrict__ Wk,
                 const float* __restrict__ Wv, const float* __restrict__ Wo,
                 const float* __restrict__ W1, const float* __restrict__ W2,
                 const float* __restrict__ lin1W, const float* __restrict__ lin2W,
                 const float* __restrict__ lin1b,
                 const float* __restrict__ cat_table, const float* __restrict__ amount_table,
                 bf16* __restrict__ Wd, float* __restrict__ bias1024,
                 bf16* __restrict__ catb, bf16* __restrict__ amtb) {
    const int z = blockIdx.z;
    const int tid = threadIdx.x;
    if (z == 8) {   // cat_table -> bf16, 128000 elems
        const int gid = (blockIdx.x * 16 + blockIdx.y) * 256 + tid;
        for (int i = gid; i < 1000 * 128; i += 65536)
            catb[i] = __float2bfloat16(cat_table[i]);
        return;
    }
    if (z == 9) {   // amount_table -> bf16, 12800 elems
        const int gid = (blockIdx.x * 16 + blockIdx.y) * 256 + tid;
        for (int i = gid; i < 100 * 128; i += 65536)
            amtb[i] = __float2bfloat16(amount_table[i]);
        return;
    }
    const float* src; bf16* dst; int Kd, Nd, sK, sN;
    switch (z) {
        case 0: src = Wq;    dst = Wd;          Kd = 128;  Nd = 128;  sK = 128;  sN = 128;  break;
        case 1: src = Wk;    dst = Wd + 16384;  Kd = 128;  Nd = 128;  sK = 128;  sN = 128;  break;
        case 2: src = Wv;    dst = Wd + 32768;  Kd = 128;  Nd = 128;  sK = 128;  sN = 128;  break;
        case 3: src = Wo;    dst = Wd + 49152;  Kd = 128;  Nd = 128;  sK = 128;  sN = 128;  break;
        case 4: src = W1;    dst = Wd + 65536;  Kd = 128;  Nd = 128;  sK = 128;  sN = 128;  break;
        case 5: src = W2;    dst = Wd + 81920;  Kd = 128;  Nd = 128;  sK = 128;  sN = 128;  break;
        case 6: src = lin1W; dst = Wd + 98304;  Kd = 128;  Nd = 1024; sK = 128;  sN = 1000; break;
        default:src = lin2W; dst = Wd + 229376; Kd = 1024; Nd = 1024; sK = 1000; sN = 1000; break;
    }
    if (z == 7 && blockIdx.x == 0 && blockIdx.y == 0) {
        for (int i = tid; i < 1024; i += 256)
            bias1024[i] = (i < 1000) ? lin1b[i] : 0.f;
    }
    const int k0 = blockIdx.x * 64, n0 = blockIdx.y * 64;
    if (k0 >= Kd || n0 >= Nd) return;
    __shared__ float t[64][65];
    const int c = tid & 63, r0 = tid >> 6;
    #pragma unroll 4
    for (int i = 0; i < 16; ++i) {
        const int r = r0 + i * 4;
        const int gk = k0 + r, gn = n0 + c;
        t[r][c] = (gk < sK && gn < sN) ? src[(size_t)gk * sN + gn] : 0.f;
    }
    __syncthreads();
    #pragma unroll 4
    for (int i = 0; i < 16; ++i) {
        const int r = r0 + i * 4;
        dst[(size_t)(n0 + r) * Kd + (k0 + c)] = __float2bfloat16(t[c][r]);
    }
}

// ---------------------------------------------------------------------------
// Embedding v3: 2 tokens/block; per token 4 j-groups x 32 lanes x 4 elems.
// 16-deep gather chains, maskless fmaf, LDS 4-way reduce. Writes f32 X only.
// ---------------------------------------------------------------------------
__global__ __launch_bounds__(256)
void embed_kernel(const int* __restrict__ cat_arr, const int* __restrict__ dt_arr,
                  const int* __restrict__ amount_arr, const int* __restrict__ id_arr,
                  const float* __restrict__ id_table, const bf16* __restrict__ catb,
                  const bf16* __restrict__ amtb, const float* __restrict__ dt_table,
                  float* __restrict__ x) {
    __shared__ int cs[2][64];
    __shared__ int as_[2][64];
    __shared__ f32x4 red[2][4][32];
    const int tid = threadIdx.x;
    const int g2 = tid >> 7;              // token slot in block
    const int t7 = tid & 127;
    const int jg = t7 >> 5;               // j-group 0..3
    const int lg = t7 & 31;               // elems lg*4 .. lg*4+3
    const int t = blockIdx.x * 2 + g2;
    const int b = t / S_, s = t - b * S_;

    if (s > 0) {
        const int base = (b * L_ + (s - 1)) * J_;
        if (t7 < 64) cs[g2][t7] = cat_arr[base + t7];
        else         as_[g2][t7 - 64] = amount_arr[base + t7 - 64];
    }
    __syncthreads();

    f32x4 acc = {0.f, 0.f, 0.f, 0.f};
    if (s > 0) {
        #pragma unroll
        for (int jj = 0; jj < 16; ++jj) {
            const int j = jg * 16 + jj;
            const int c = cs[g2][j];
            const float m = (c != CAT_) ? 1.f : 0.f;
            const int ci = (c != CAT_) ? c : 0;
            const ushort4 cu = *(const ushort4*)(catb + (size_t)ci * E_ + lg * 4);
            const ushort4 au = *(const ushort4*)(amtb + (size_t)as_[g2][j] * E_ + lg * 4);
            acc[0] = fmaf(m, bf2f(cu.x) + bf2f(au.x), acc[0]);
            acc[1] = fmaf(m, bf2f(cu.y) + bf2f(au.y), acc[1]);
            acc[2] = fmaf(m, bf2f(cu.z) + bf2f(au.z), acc[2]);
            acc[3] = fmaf(m, bf2f(cu.w) + bf2f(au.w), acc[3]);
        }
    }
    red[g2][jg][lg] = acc;
    __syncthreads();

    if (jg == 0) {
        const size_t off = (size_t)t * E_ + lg * 4;
        if (s == 0) {
            *(float4*)(x + off) =
                *(const float4*)(id_table + (size_t)id_arr[b] * E_ + lg * 4);
        } else {
            const f32x4 a0 = red[g2][0][lg], a1 = red[g2][1][lg];
            const f32x4 a2 = red[g2][2][lg], a3 = red[g2][3][lg];
            const float4 dv = *(const float4*)(
                dt_table + (size_t)dt_arr[b * L_ + s - 1] * E_ + lg * 4);
            float4 o;
            o.x = a0[0] + a1[0] + a2[0] + a3[0] + dv.x;
            o.y = a0[1] + a1[1] + a2[1] + a3[1] + dv.y;
            o.z = a0[2] + a1[2] + a2[2] + a3[2] + dv.z;
            o.w = a0[3] + a1[3] + a2[3] + a3[3] + dv.w;
            *(float4*)(x + off) = o;
        }
    }
}

// ---------------------------------------------------------------------------
// bf16 MFMA GEMM: C = A[M,K] @ Bt[N,K]bf16 (+bias)(+resid)(relu|LN)
// AF32: A is f32, converted to bf16 during LDS staging.
// QKV: blockIdx.y selects weight/bias/output slice {Q,K,V} (N=128 each).
// SPLITK: gridDim.z parts; f32 partials at Cf + z*M*Nstride, bias skipped.
// ---------------------------------------------------------------------------
template<bool RELU, bool LN, bool HASRES, bool OF32, bool OBF16, bool SPLITK,
         bool AF32, bool QKV>
__global__ __launch_bounds__(256)
void gemm_mfma(const void* __restrict__ Av, const bf16* __restrict__ Bt,
               const float* __restrict__ bias, const float* __restrict__ bias2,
               const float* __restrict__ bias3, const float* __restrict__ resid,
               float* __restrict__ Cf, bf16* __restrict__ Cb,
               bf16* __restrict__ Cb2, bf16* __restrict__ Cb3,
               const float* __restrict__ lng, const float* __restrict__ lnb,
               int K, int Nstride, int Nstore) {
    __shared__ bf16x8 Al[64 * 16];    // 16 KiB
    __shared__ bf16x8 Bl[128 * 16];   // 32 KiB
    const int tid = threadIdx.x;
    const int m0 = blockIdx.x * 64;
    const int n0 = QKV ? 0 : blockIdx.y * 128;
    const int w = tid >> 6, l = tid & 63;
    const int l15 = l & 15, g = l >> 4;
    f32x4 acc[8] = {};

    const bf16* BtX = Bt;
    const float* biasX = bias;
    bf16* CbX = Cb;
    if (QKV) {
        const int sel = blockIdx.y;
        BtX = Bt + sel * 16384;
        biasX = (sel == 0) ? bias : ((sel == 1) ? bias2 : bias3);
        CbX = (sel == 0) ? Cb : ((sel == 1) ? Cb2 : Cb3);
    }

    const int z = SPLITK ? blockIdx.z : 0;
    const int ksz = SPLITK ? (K / (int)gridDim.z) : K;
    const int kbeg = z * ksz;

    for (int kc = kbeg; kc < kbeg + ksz; kc += 128) {
        #pragma unroll
        for (int i = 0; i < 4; ++i) {
            const int lin = i * 256 + tid;
            const int r = lin >> 4, u = lin & 15;
            bf16x8 av;
            if (AF32) {
                const float* Af = (const float*)Av;
                const float4 f0 = *(const float4*)(Af + (size_t)(m0 + r) * K + kc + u * 8);
                const float4 f1 = *(const float4*)(Af + (size_t)(m0 + r) * K + kc + u * 8 + 4);
                av[0] = (short)f2bu(f0.x); av[1] = (short)f2bu(f0.y);
                av[2] = (short)f2bu(f0.z); av[3] = (short)f2bu(f0.w);
                av[4] = (short)f2bu(f1.x); av[5] = (short)f2bu(f1.y);
                av[6] = (short)f2bu(f1.z); av[7] = (short)f2bu(f1.w);
            } else {
                const bf16* Ab = (const bf16*)Av;
                av = *(const bf16x8*)(Ab + (size_t)(m0 + r) * K + kc + u * 8);
            }
            Al[r * 16 + (u ^ (r & 7))] = av;
        }
        #pragma unroll
        for (int i = 0; i < 8; ++i) {
            const int lin = i * 256 + tid;
            const int r = lin >> 4, u = lin & 15;
            Bl[r * 16 + (u ^ (r & 7))] =
                *(const bf16x8*)(BtX + (size_t)(n0 + r) * K + kc + u * 8);
        }
        __syncthreads();
        const int mr = w * 16 + l15;
        #pragma unroll
        for (int s = 0; s < 4; ++s) {
            const int ua = s * 4 + g;
            const bf16x8 a = Al[mr * 16 + (ua ^ (mr & 7))];
            #pragma unroll
            for (int nf = 0; nf < 8; ++nf) {
                const int nr = nf * 16 + l15;
                const bf16x8 b = Bl[nr * 16 + (ua ^ (nr & 7))];
                acc[nf] = __builtin_amdgcn_mfma_f32_16x16x32_bf16(a, b, acc[nf], 0, 0, 0);
            }
        }
        __syncthreads();
    }

    // epilogue: lane l owns rows w*16+g*4+fr, cols nf*16+l15
    #pragma unroll
    for (int fr = 0; fr < 4; ++fr) {
        const int grow = m0 + w * 16 + g * 4 + fr;
        float v[8];
        float s1 = 0.f, s2 = 0.f;
        #pragma unroll
        for (int nf = 0; nf < 8; ++nf) {
            const int col = n0 + nf * 16 + l15;
            float xv = acc[nf][fr];
            if (!SPLITK && col < Nstore) xv += biasX[col];
            if (HASRES) xv += resid[(size_t)grow * Nstride + col];
            if (RELU) xv = fmaxf(xv, 0.f);
            v[nf] = xv;
            if (LN) { s1 += xv; s2 += xv * xv; }
        }
        if (LN) {
            #pragma unroll
            for (int off = 1; off < 16; off <<= 1) {
                s1 += __shfl_xor(s1, off);
                s2 += __shfl_xor(s2, off);
            }
            const float mu = s1 * (1.f / 128.f);
            const float rstd = rsqrtf(s2 * (1.f / 128.f) - mu * mu + LN_EPS);
            #pragma unroll
            for (int nf = 0; nf < 8; ++nf) {
                const int col = n0 + nf * 16 + l15;
                v[nf] = (v[nf] - mu) * rstd * lng[col] + lnb[col];
            }
        }
        float* Cfp = SPLITK ? (Cf + (size_t)z * (gridDim.x * 64) * Nstride) : Cf;
        #pragma unroll
        for (int nf = 0; nf < 8; ++nf) {
            const int col = n0 + nf * 16 + l15;
            if (col < Nstore) {
                if (OF32)  Cfp[(size_t)grow * Nstride + col] = v[nf];
                if (OBF16) CbX[(size_t)grow * Nstride + col] = __float2bfloat16(v[nf]);
            }
        }
    }
}

// ---------------------------------------------------------------------------
// MFMA attention: one block per (b,h). Whole-head in LDS.
// Qs/Ks: [144 rows][8 units] bf16x8, XOR-swizzled. Vt: V^T [64][168] bf16.
// Sc: f32 scores [129][132]; P (bf16) written in-place over Sc rows.
// O written in-place into qb (block owns its (b,h) slice).
// ---------------------------------------------------------------------------
__global__ __launch_bounds__(256)
void attn_mfma(bf16* __restrict__ qb, const bf16* __restrict__ kb,
               const bf16* __restrict__ vb) {
    __shared__ __align__(16) bf16x8 Qs[144 * 8];
    __shared__ __align__(16) bf16x8 Ks[144 * 8];
    __shared__ __align__(16) bf16  Vt[64 * 168];
    __shared__ __align__(16) float Sc[129 * 132];
    const int tid = threadIdx.x;
    const int w = tid >> 6, l = tid & 63;
    const int l15 = l & 15, g = l >> 4;
    const int h = blockIdx.x & (H_ - 1);
    const int b = blockIdx.x >> 1;
    const size_t base = ((size_t)b * S_) * E_ + h * HD;

    // stage Q,K: row r, unit u (8 bf16), swizzled u^(r&7)
    for (int idx = tid; idx < S_ * 8; idx += 256) {
        const int r = idx >> 3, u = idx & 7;
        const int us = u ^ (r & 7);
        Qs[r * 8 + us] = *(const bf16x8*)(qb + base + (size_t)r * E_ + u * 8);
        Ks[r * 8 + us] = *(const bf16x8*)(kb + base + (size_t)r * E_ + u * 8);
    }
    // stage V transposed; zero pad t in [129,168)
    for (int idx = tid; idx < 168 * 64; idx += 256) {
        const int t = idx >> 6, d = idx & 63;
        const bf16 val = (t < S_) ? vb[base + (size_t)t * E_ + d]
                                  : __float2bfloat16(0.f);
        Vt[d * 168 + t] = val;
    }
    __syncthreads();

    // QK^T: 81 tiles (9x9 of 16x16), K=64 (2 MFMA each)
    for (int i = w; i < 81; i += 4) {
        const int rt = i / 9, ct = i - rt * 9;
        const int qr = rt * 16 + l15;          // < 144, in-bounds
        const int kr = ct * 16 + l15;
        f32x4 acc = {};
        #pragma unroll
        for (int s = 0; s < 2; ++s) {
            const int ua = s * 4 + g;
            acc = __builtin_amdgcn_mfma_f32_16x16x32_bf16(
                Qs[qr * 8 + (ua ^ (qr & 7))], Ks[kr * 8 + (ua ^ (kr & 7))],
                acc, 0, 0, 0);
        }
        const int col = ct * 16 + l15;
        #pragma unroll
        for (int r = 0; r < 4; ++r) {
            const int row = rt * 16 + g * 4 + r;
            // col<132: ct=8 writes cols 128..143; cols >=132 would overflow
            // the row stride and corrupt the next row's cols 0..11.
            if (row < S_ && col < 132) Sc[row * 132 + col] = acc[r] * 0.125f;
        }
    }
    __syncthreads();

    // wave-parallel softmax; write bf16 P in-place over each Sc row
    for (int r = w; r < S_; r += 4) {
        float* Srow = Sc + r * 132;
        const float e0 = Srow[l];
        const float e1 = Srow[l + 64];
        const float e2 = (l == 0) ? Srow[128] : -1e30f;
        float m = fmaxf(fmaxf(e0, e1), e2);
        #pragma unroll
        for (int off = 1; off < 64; off <<= 1) m = fmaxf(m, __shfl_xor(m, off));
        const float p0 = __expf(e0 - m);
        const float p1 = __expf(e1 - m);
        const float p2 = (l == 0) ? __expf(e2 - m) : 0.f;
        float s = p0 + p1 + p2;
        #pragma unroll
        for (int off = 1; off < 64; off <<= 1) s += __shfl_xor(s, off);
        const float inv = 1.f / s;
        bf16* Prow = (bf16*)Srow;
        Prow[l] = __float2bfloat16(p0 * inv);
        Prow[l + 64] = __float2bfloat16(p1 * inv);
        if (l == 0) Prow[128] = __float2bfloat16(p2 * inv);
        if (l < 31) Prow[129 + l] = __float2bfloat16(0.f);   // zero k-pad 129..159
    }
    __syncthreads();

    // PV: O[129][64] = P[129][160] @ V[160][64]; 36 tiles x 5 k-chunks
    for (int i = w; i < 36; i += 4) {
        const int rt = i >> 2, ct = i & 3;
        int pr = rt * 16 + l15; if (pr > 128) pr = 128;   // clamp: rows >=129 unstored
        const bf16* Prow = (const bf16*)(Sc + pr * 132);
        const bf16* Vrow = Vt + (ct * 16 + l15) * 168;
        f32x4 acc = {};
        #pragma unroll
        for (int kc = 0; kc < 5; ++kc) {
            const bf16x8 a = *(const bf16x8*)(Prow + kc * 32 + g * 8);
            const bf16x8 bb = *(const bf16x8*)(Vrow + kc * 32 + g * 8);
            acc = __builtin_amdgcn_mfma_f32_16x16x32_bf16(a, bb, acc, 0, 0, 0);
        }
        #pragma unroll
        for (int r = 0; r < 4; ++r) {
            const int orow = rt * 16 + g * 4 + r;
            if (orow < S_)
                qb[base + (size_t)orow * E_ + ct * 16 + l15] =
                    __float2bfloat16(acc[r]);
        }
    }
}

// mean-pool tokens 1..128 -> bf16 h[B,E]
__global__ __launch_bounds__(128)
void pool_kernel(const float* __restrict__ X2, bf16* __restrict__ Hout) {
    const int b = blockIdx.x, e = threadIdx.x;
    float acc = 0.f;
    for (int s = 1; s < S_; ++s) acc += X2[((size_t)b * S_ + s) * E_ + e];
    Hout[(size_t)b * E_ + e] = __float2bfloat16(acc * (1.f / 128.f));
}

// reduce split-K partials [4][128][1024] -> out[128][1000] (+bias)
__global__ __launch_bounds__(256)
void splitk_reduce(const float* __restrict__ part, const float* __restrict__ bias,
                   float* __restrict__ out) {
    const int i = blockIdx.x * 256 + threadIdx.x;
    if (i >= B_ * CAT_) return;
    const int m = i / CAT_, n = i - m * CAT_;
    float v = bias[n];
    #pragma unroll
    for (int z = 0; z < 4; ++z) v += part[(size_t)z * 131072 + m * 1024 + n];
    out[i] = v;
}

// ---------------------------------------------------------------------------
extern "C" void kernel_launch(void* const* d_in, const int* in_sizes, int n_in,
                              void* d_out, int out_size, void* d_ws, size_t ws_size,
                              hipStream_t stream) {
    const int* cat_arr      = (const int*)d_in[0];
    const int* dt_arr       = (const int*)d_in[1];
    const int* amount_arr   = (const int*)d_in[2];
    const int* id_arr       = (const int*)d_in[3];
    const float* id_table   = (const float*)d_in[4];
    const float* cat_table  = (const float*)d_in[5];
    const float* amount_tab = (const float*)d_in[6];
    const float* dt_table   = (const float*)d_in[7];
    const float* Wq = (const float*)d_in[8];  const float* bq = (const float*)d_in[9];
    const float* Wk = (const float*)d_in[10]; const float* bk = (const float*)d_in[11];
    const float* Wv = (const float*)d_in[12]; const float* bv = (const float*)d_in[13];
    const float* Wo = (const float*)d_in[14]; const float* bo = (const float*)d_in[15];
    const float* ln1_g = (const float*)d_in[16]; const float* ln1_b = (const float*)d_in[17];
    const float* W1 = (const float*)d_in[18]; const float* b1 = (const float*)d_in[19];
    const float* W2 = (const float*)d_in[20]; const float* b2 = (const float*)d_in[21];
    const float* ln2_g = (const float*)d_in[22]; const float* ln2_b = (const float*)d_in[23];
    const float* lin1_W = (const float*)d_in[24]; const float* lin1_b = (const float*)d_in[25];
    const float* lin2_W = (const float*)d_in[26]; const float* lin2_b = (const float*)d_in[27];
    float* out = (float*)d_out;
    float* ws = (float*)d_ws;

    // Workspace (floats), total ~23.9 MiB:
    //   X[ME] | C0 bf16[ME] | D0 bf16[ME] | E0 bf16[ME] | Wd | bias1024 | catb | amtb
    const size_t ME = (size_t)M_ * E_;           // 2,113,536
    float* X  = ws;                               // f32 x -> x1 -> x2 (in-place)
    bf16* C0  = (bf16*)(ws + ME);                 // Kb -> X1b -> F1b
    bf16* D0  = (bf16*)(ws + ME + ME / 2);        // Qb -> Ob -> hbb/a1b
    bf16* E0  = (bf16*)(ws + 2 * ME);             // Vb -> (f32 prt)
    bf16* Wd  = (bf16*)(ws + 2 * ME + ME / 2);    // 1,277,952 bf16
    float* bias1024 = ws + 2 * ME + ME / 2 + 638976;
    bf16* catb = (bf16*)(bias1024 + 1024);        // [1000][128] bf16
    bf16* amtb = catb + 128000;                   // [100][128] bf16
    bf16* hbb = D0;                               // [128][128]
    bf16* a1b = D0 + 16384;                       // [128][1024]
    float* prt = (float*)E0;                      // [4][128][1024] f32 (2 MiB)

    prep_kernel<<<dim3(16, 16, 10), 256, 0, stream>>>(
        Wq, Wk, Wv, Wo, W1, W2, lin1_W, lin2_W, lin1_b,
        cat_table, amount_tab, Wd, bias1024, catb, amtb);

    embed_kernel<<<M_ / 2, 256, 0, stream>>>(cat_arr, dt_arr, amount_arr, id_arr,
                                             id_table, catb, amtb, dt_table, X);

    // Fused QKV from f32 X: sel 0->Q(D0), 1->K(C0), 2->V(E0)
    gemm_mfma<false,false,false,false,true,false,true,true>
        <<<dim3(M_ / 64, 3), 256, 0, stream>>>(
        X, Wd, bq, bk, bv, nullptr, nullptr, D0, C0, E0, nullptr, nullptr,
        128, 128, 128);

    attn_mfma<<<B_ * H_, 256, 0, stream>>>(D0, C0, E0);       // Ob -> D0

    const dim3 gE(M_ / 64, 1);
    // X1 = LN1(X + Ob@Wo + bo): f32 in-place X, bf16 X1b -> C0 (K dead)
    gemm_mfma<false,true,true,true,true,false,false,false><<<gE, 256, 0, stream>>>(
        D0, Wd + 49152, bo, nullptr, nullptr, X, X, C0, nullptr, nullptr,
        ln1_g, ln1_b, 128, 128, 128);
    // F1b = relu(X1b@W1 + b1) -> C0 in-place (block-row-aligned)
    gemm_mfma<true,false,false,false,true,false,false,false><<<gE, 256, 0, stream>>>(
        C0, Wd + 65536, b1, nullptr, nullptr, nullptr, nullptr, C0, nullptr, nullptr,
        nullptr, nullptr, 128, 128, 128);
    // X2 = LN2(X1 + F1b@W2 + b2): f32 in-place X
    gemm_mfma<false,true,true,true,false,false,false,false><<<gE, 256, 0, stream>>>(
        C0, Wd + 81920, b2, nullptr, nullptr, X, X, nullptr, nullptr, nullptr,
        ln2_g, ln2_b, 128, 128, 128);

    pool_kernel<<<B_, 128, 0, stream>>>(X, hbb);

    // a1b = relu(hbb@lin1 + b) [128][1024]
    gemm_mfma<true,false,false,false,true,false,false,false>
        <<<dim3(2, 8), 256, 0, stream>>>(
        hbb, Wd + 98304, bias1024, nullptr, nullptr, nullptr, nullptr, a1b,
        nullptr, nullptr, nullptr, nullptr, 128, 1024, 1024);
    // prt[z] = a1b@lin2 partials (K=1024 split 4 ways)
    gemm_mfma<false,false,false,true,false,true,false,false>
        <<<dim3(2, 8, 4), 256, 0, stream>>>(
        a1b, Wd + 229376, nullptr, nullptr, nullptr, nullptr, prt, nullptr,
        nullptr, nullptr, nullptr, nullptr, 1024, 1024, 1024);
    splitk_reduce<<<(B_ * CAT_ + 255) / 256, 256, 0, stream>>>(prt, lin2_b, out);
}

// Round 8
// 149.167 us; speedup vs baseline: 2.6914x; 1.1272x over previous
//
#include <hip/hip_runtime.h>
#include <hip/hip_bf16.h>

#define B_ 128
#define L_ 128
#define J_ 64
#define E_ 128
#define H_ 2
#define HD 64
#define S_ 129          // L+1
#define M_ (B_ * S_)    // 16512 tokens
#define CAT_ 1000
#define LN_EPS 1e-5f

typedef __attribute__((ext_vector_type(8))) short bf16x8;
typedef __attribute__((ext_vector_type(4))) float f32x4;
typedef __hip_bfloat16 bf16;

__device__ inline float bf2f(unsigned short u) {
    union { unsigned int i; float f; } v; v.i = (unsigned int)u << 16; return v.f;
}
__device__ inline unsigned short f2bu(float f) {
    __hip_bfloat16 h = __float2bfloat16(f);
    return *reinterpret_cast<unsigned short*>(&h);
}

// ---------------------------------------------------------------------------
// prep: transpose+convert weights to bf16 Bt[N][K]; pad lin1/lin2; pad bias;
// z=8/9: convert cat/amount tables to bf16 (row-layout unchanged).
// Wd bf16 offsets: q=0 k=16384 v=32768 o=49152 w1=65536 w2=81920
//                  lin1=98304 ([1024][128]) lin2=229376 ([1024][1024])
// ---------------------------------------------------------------------------
__global__ __launch_bounds__(256)
void prep_kernel(const float* __restrict__ Wq, const float* __restrict__ Wk,
                 const float* __restrict__ Wv, const float* __restrict__ Wo,
                 const float* __restrict__ W1, const float* __restrict__ W2,
                 const float* __restrict__ lin1W, const float* __restrict__ lin2W,
                 const float* __restrict__ lin1b,
                 const float* __restrict__ cat_table, const float* __restrict__ amount_table,
                 bf16* __restrict__ Wd, float* __restrict__ bias1024,
                 bf16* __restrict__ catb, bf16* __restrict__ amtb) {
    const int z = blockIdx.z;
    const int tid = threadIdx.x;
    if (z == 8) {   // cat_table -> bf16, 128000 elems
        const int gid = (blockIdx.x * 16 + blockIdx.y) * 256 + tid;
        for (int i = gid; i < 1000 * 128; i += 65536)
            catb[i] = __float2bfloat16(cat_table[i]);
        return;
    }
    if (z == 9) {   // amount_table -> bf16, 12800 elems
        const int gid = (blockIdx.x * 16 + blockIdx.y) * 256 + tid;
        for (int i = gid; i < 100 * 128; i += 65536)
            amtb[i] = __float2bfloat16(amount_table[i]);
        return;
    }
    const float* src; bf16* dst; int Kd, Nd, sK, sN;
    switch (z) {
        case 0: src = Wq;    dst = Wd;          Kd = 128;  Nd = 128;  sK = 128;  sN = 128;  break;
        case 1: src = Wk;    dst = Wd + 16384;  Kd = 128;  Nd = 128;  sK = 128;  sN = 128;  break;
        case 2: src = Wv;    dst = Wd + 32768;  Kd = 128;  Nd = 128;  sK = 128;  sN = 128;  break;
        case 3: src = Wo;    dst = Wd + 49152;  Kd = 128;  Nd = 128;  sK = 128;  sN = 128;  break;
        case 4: src = W1;    dst = Wd + 65536;  Kd = 128;  Nd = 128;  sK = 128;  sN = 128;  break;
        case 5: src = W2;    dst = Wd + 81920;  Kd = 128;  Nd = 128;  sK = 128;  sN = 128;  break;
        case 6: src = lin1W; dst = Wd + 98304;  Kd = 128;  Nd = 1024; sK = 128;  sN = 1000; break;
        default:src = lin2W; dst = Wd + 229376; Kd = 1024; Nd = 1024; sK = 1000; sN = 1000; break;
    }
    if (z == 7 && blockIdx.x == 0 && blockIdx.y == 0) {
        for (int i = tid; i < 1024; i += 256)
            bias1024[i] = (i < 1000) ? lin1b[i] : 0.f;
    }
    const int k0 = blockIdx.x * 64, n0 = blockIdx.y * 64;
    if (k0 >= Kd || n0 >= Nd) return;
    __shared__ float t[64][65];
    const int c = tid & 63, r0 = tid >> 6;
    #pragma unroll 4
    for (int i = 0; i < 16; ++i) {
        const int r = r0 + i * 4;
        const int gk = k0 + r, gn = n0 + c;
        t[r][c] = (gk < sK && gn < sN) ? src[(size_t)gk * sN + gn] : 0.f;
    }
    __syncthreads();
    #pragma unroll 4
    for (int i = 0; i < 16; ++i) {
        const int r = r0 + i * 4;
        dst[(size_t)(n0 + r) * Kd + (k0 + c)] = __float2bfloat16(t[c][r]);
    }
}

// ---------------------------------------------------------------------------
// Embedding v3: 2 tokens/block; per token 4 j-groups x 32 lanes x 4 elems.
// ---------------------------------------------------------------------------
__global__ __launch_bounds__(256)
void embed_kernel(const int* __restrict__ cat_arr, const int* __restrict__ dt_arr,
                  const int* __restrict__ amount_arr, const int* __restrict__ id_arr,
                  const float* __restrict__ id_table, const bf16* __restrict__ catb,
                  const bf16* __restrict__ amtb, const float* __restrict__ dt_table,
                  float* __restrict__ x) {
    __shared__ int cs[2][64];
    __shared__ int as_[2][64];
    __shared__ f32x4 red[2][4][32];
    const int tid = threadIdx.x;
    const int g2 = tid >> 7;              // token slot in block
    const int t7 = tid & 127;
    const int jg = t7 >> 5;               // j-group 0..3
    const int lg = t7 & 31;               // elems lg*4 .. lg*4+3
    const int t = blockIdx.x * 2 + g2;
    const int b = t / S_, s = t - b * S_;

    if (s > 0) {
        const int base = (b * L_ + (s - 1)) * J_;
        if (t7 < 64) cs[g2][t7] = cat_arr[base + t7];
        else         as_[g2][t7 - 64] = amount_arr[base + t7 - 64];
    }
    __syncthreads();

    f32x4 acc = {0.f, 0.f, 0.f, 0.f};
    if (s > 0) {
        #pragma unroll
        for (int jj = 0; jj < 16; ++jj) {
            const int j = jg * 16 + jj;
            const int c = cs[g2][j];
            const float m = (c != CAT_) ? 1.f : 0.f;
            const int ci = (c != CAT_) ? c : 0;
            const ushort4 cu = *(const ushort4*)(catb + (size_t)ci * E_ + lg * 4);
            const ushort4 au = *(const ushort4*)(amtb + (size_t)as_[g2][j] * E_ + lg * 4);
            acc[0] = fmaf(m, bf2f(cu.x) + bf2f(au.x), acc[0]);
            acc[1] = fmaf(m, bf2f(cu.y) + bf2f(au.y), acc[1]);
            acc[2] = fmaf(m, bf2f(cu.z) + bf2f(au.z), acc[2]);
            acc[3] = fmaf(m, bf2f(cu.w) + bf2f(au.w), acc[3]);
        }
    }
    red[g2][jg][lg] = acc;
    __syncthreads();

    if (jg == 0) {
        const size_t off = (size_t)t * E_ + lg * 4;
        if (s == 0) {
            *(float4*)(x + off) =
                *(const float4*)(id_table + (size_t)id_arr[b] * E_ + lg * 4);
        } else {
            const f32x4 a0 = red[g2][0][lg], a1 = red[g2][1][lg];
            const f32x4 a2 = red[g2][2][lg], a3 = red[g2][3][lg];
            const float4 dv = *(const float4*)(
                dt_table + (size_t)dt_arr[b * L_ + s - 1] * E_ + lg * 4);
            float4 o;
            o.x = a0[0] + a1[0] + a2[0] + a3[0] + dv.x;
            o.y = a0[1] + a1[1] + a2[1] + a3[1] + dv.y;
            o.z = a0[2] + a1[2] + a2[2] + a3[2] + dv.z;
            o.w = a0[3] + a1[3] + a2[3] + a3[3] + dv.w;
            *(float4*)(x + off) = o;
        }
    }
}

// ---------------------------------------------------------------------------
// bf16 MFMA GEMM (unchanged from round 7)
// ---------------------------------------------------------------------------
template<bool RELU, bool LN, bool HASRES, bool OF32, bool OBF16, bool SPLITK,
         bool AF32, bool QKV>
__global__ __launch_bounds__(256)
void gemm_mfma(const void* __restrict__ Av, const bf16* __restrict__ Bt,
               const float* __restrict__ bias, const float* __restrict__ bias2,
               const float* __restrict__ bias3, const float* __restrict__ resid,
               float* __restrict__ Cf, bf16* __restrict__ Cb,
               bf16* __restrict__ Cb2, bf16* __restrict__ Cb3,
               const float* __restrict__ lng, const float* __restrict__ lnb,
               int K, int Nstride, int Nstore) {
    __shared__ bf16x8 Al[64 * 16];    // 16 KiB
    __shared__ bf16x8 Bl[128 * 16];   // 32 KiB
    const int tid = threadIdx.x;
    const int m0 = blockIdx.x * 64;
    const int n0 = QKV ? 0 : blockIdx.y * 128;
    const int w = tid >> 6, l = tid & 63;
    const int l15 = l & 15, g = l >> 4;
    f32x4 acc[8] = {};

    const bf16* BtX = Bt;
    const float* biasX = bias;
    bf16* CbX = Cb;
    if (QKV) {
        const int sel = blockIdx.y;
        BtX = Bt + sel * 16384;
        biasX = (sel == 0) ? bias : ((sel == 1) ? bias2 : bias3);
        CbX = (sel == 0) ? Cb : ((sel == 1) ? Cb2 : Cb3);
    }

    const int z = SPLITK ? blockIdx.z : 0;
    const int ksz = SPLITK ? (K / (int)gridDim.z) : K;
    const int kbeg = z * ksz;

    for (int kc = kbeg; kc < kbeg + ksz; kc += 128) {
        #pragma unroll
        for (int i = 0; i < 4; ++i) {
            const int lin = i * 256 + tid;
            const int r = lin >> 4, u = lin & 15;
            bf16x8 av;
            if (AF32) {
                const float* Af = (const float*)Av;
                const float4 f0 = *(const float4*)(Af + (size_t)(m0 + r) * K + kc + u * 8);
                const float4 f1 = *(const float4*)(Af + (size_t)(m0 + r) * K + kc + u * 8 + 4);
                av[0] = (short)f2bu(f0.x); av[1] = (short)f2bu(f0.y);
                av[2] = (short)f2bu(f0.z); av[3] = (short)f2bu(f0.w);
                av[4] = (short)f2bu(f1.x); av[5] = (short)f2bu(f1.y);
                av[6] = (short)f2bu(f1.z); av[7] = (short)f2bu(f1.w);
            } else {
                const bf16* Ab = (const bf16*)Av;
                av = *(const bf16x8*)(Ab + (size_t)(m0 + r) * K + kc + u * 8);
            }
            Al[r * 16 + (u ^ (r & 7))] = av;
        }
        #pragma unroll
        for (int i = 0; i < 8; ++i) {
            const int lin = i * 256 + tid;
            const int r = lin >> 4, u = lin & 15;
            Bl[r * 16 + (u ^ (r & 7))] =
                *(const bf16x8*)(BtX + (size_t)(n0 + r) * K + kc + u * 8);
        }
        __syncthreads();
        const int mr = w * 16 + l15;
        #pragma unroll
        for (int s = 0; s < 4; ++s) {
            const int ua = s * 4 + g;
            const bf16x8 a = Al[mr * 16 + (ua ^ (mr & 7))];
            #pragma unroll
            for (int nf = 0; nf < 8; ++nf) {
                const int nr = nf * 16 + l15;
                const bf16x8 b = Bl[nr * 16 + (ua ^ (nr & 7))];
                acc[nf] = __builtin_amdgcn_mfma_f32_16x16x32_bf16(a, b, acc[nf], 0, 0, 0);
            }
        }
        __syncthreads();
    }

    #pragma unroll
    for (int fr = 0; fr < 4; ++fr) {
        const int grow = m0 + w * 16 + g * 4 + fr;
        float v[8];
        float s1 = 0.f, s2 = 0.f;
        #pragma unroll
        for (int nf = 0; nf < 8; ++nf) {
            const int col = n0 + nf * 16 + l15;
            float xv = acc[nf][fr];
            if (!SPLITK && col < Nstore) xv += biasX[col];
            if (HASRES) xv += resid[(size_t)grow * Nstride + col];
            if (RELU) xv = fmaxf(xv, 0.f);
            v[nf] = xv;
            if (LN) { s1 += xv; s2 += xv * xv; }
        }
        if (LN) {
            #pragma unroll
            for (int off = 1; off < 16; off <<= 1) {
                s1 += __shfl_xor(s1, off);
                s2 += __shfl_xor(s2, off);
            }
            const float mu = s1 * (1.f / 128.f);
            const float rstd = rsqrtf(s2 * (1.f / 128.f) - mu * mu + LN_EPS);
            #pragma unroll
            for (int nf = 0; nf < 8; ++nf) {
                const int col = n0 + nf * 16 + l15;
                v[nf] = (v[nf] - mu) * rstd * lng[col] + lnb[col];
            }
        }
        float* Cfp = SPLITK ? (Cf + (size_t)z * (gridDim.x * 64) * Nstride) : Cf;
        #pragma unroll
        for (int nf = 0; nf < 8; ++nf) {
            const int col = n0 + nf * 16 + l15;
            if (col < Nstore) {
                if (OF32)  Cfp[(size_t)grow * Nstride + col] = v[nf];
                if (OBF16) CbX[(size_t)grow * Nstride + col] = __float2bfloat16(v[nf]);
            }
        }
    }
}

// ---------------------------------------------------------------------------
// MFMA attention v2: block = (b, h, half). half0 owns q-tiles {0..4},
// half1 owns {5..8}. Scores/softmax in REGISTERS (acc[9] per wave-tile);
// P staged in a per-wave 16x168 bf16 LDS buffer (no barrier: same-wave DS
// ordering). LDS = Ks 18K + Vt 21K + Pb 21K = 60KB -> 2 blocks/CU.
// O written in-place into qb (each wave reads its Q rows before writing).
// ---------------------------------------------------------------------------
__global__ __launch_bounds__(256)
void attn_mfma(bf16* __restrict__ qb, const bf16* __restrict__ kb,
               const bf16* __restrict__ vb) {
    __shared__ __align__(16) bf16x8 Ks[144 * 8];      // 18 KiB, swizzled
    __shared__ __align__(16) bf16  Vt[64 * 168];      // 21 KiB, V^T
    __shared__ __align__(16) bf16  Pb[4][16 * 168];   // 21 KiB, per-wave P
    const int tid = threadIdx.x;
    const int w = tid >> 6, l = tid & 63;
    const int l15 = l & 15, g = l >> 4;
    const int blk = blockIdx.x;
    const int half = blk & 1;
    const int h = (blk >> 1) & (H_ - 1);
    const int b = blk >> 2;
    const size_t base = ((size_t)b * S_) * E_ + h * HD;

    // stage K rows 0..143 (zero-fill >=129), swizzled u^(r&7)
    for (int idx = tid; idx < 144 * 8; idx += 256) {
        const int r = idx >> 3, u = idx & 7;
        bf16x8 kv = {0, 0, 0, 0, 0, 0, 0, 0};
        if (r < S_) kv = *(const bf16x8*)(kb + base + (size_t)r * E_ + u * 8);
        Ks[r * 8 + (u ^ (r & 7))] = kv;
    }
    // stage V transposed; zero pad t in [129,168)
    for (int idx = tid; idx < 168 * 64; idx += 256) {
        const int t = idx >> 6, d = idx & 63;
        Vt[d * 168 + t] = (t < S_) ? vb[base + (size_t)t * E_ + d]
                                   : __float2bfloat16(0.f);
    }
    __syncthreads();

    bf16* P = Pb[w];
    for (int rt = (half ? 5 : 0) + w; rt < (half ? 9 : 5); rt += 4) {
        // Q fragments direct from global (row clamp only triggers for rt=8)
        const int qr0 = rt * 16 + l15;
        const int qrow = (qr0 < S_) ? qr0 : (S_ - 1);
        const bf16x8 aq0 = *(const bf16x8*)(qb + base + (size_t)qrow * E_ + g * 8);
        const bf16x8 aq1 = *(const bf16x8*)(qb + base + (size_t)qrow * E_ + 32 + g * 8);

        // QK^T row-strip: 9 col-tiles into registers
        f32x4 acc[9];
        #pragma unroll
        for (int ct = 0; ct < 9; ++ct) {
            const int kr = ct * 16 + l15;
            f32x4 a = {0.f, 0.f, 0.f, 0.f};
            a = __builtin_amdgcn_mfma_f32_16x16x32_bf16(
                    aq0, Ks[kr * 8 + (g ^ (kr & 7))], a, 0, 0, 0);
            a = __builtin_amdgcn_mfma_f32_16x16x32_bf16(
                    aq1, Ks[kr * 8 + ((4 + g) ^ (kr & 7))], a, 0, 0, 0);
            acc[ct] = a;
        }

        // in-register softmax; lane holds rows g*4+r, col ct*16+l15
        const bool tail = (l15 != 0);      // ct=8 valid only at l15==0
        float mx[4] = {-1e30f, -1e30f, -1e30f, -1e30f};
        #pragma unroll
        for (int ct = 0; ct < 9; ++ct)
            #pragma unroll
            for (int r = 0; r < 4; ++r) {
                const float v = acc[ct][r] * 0.125f;
                acc[ct][r] = v;
                if (ct < 8 || !tail) mx[r] = fmaxf(mx[r], v);
            }
        #pragma unroll
        for (int r = 0; r < 4; ++r)
            #pragma unroll
            for (int off = 1; off < 16; off <<= 1)
                mx[r] = fmaxf(mx[r], __shfl_xor(mx[r], off));
        float sm[4] = {0.f, 0.f, 0.f, 0.f};
        #pragma unroll
        for (int ct = 0; ct < 9; ++ct)
            #pragma unroll
            for (int r = 0; r < 4; ++r) {
                const float p = (ct < 8 || !tail) ? __expf(acc[ct][r] - mx[r]) : 0.f;
                acc[ct][r] = p;
                sm[r] += p;
            }
        #pragma unroll
        for (int r = 0; r < 4; ++r) {
            #pragma unroll
            for (int off = 1; off < 16; off <<= 1)
                sm[r] += __shfl_xor(sm[r], off);
            sm[r] = 1.f / sm[r];
        }

        // P -> per-wave LDS (row g*4+r, col ct*16+l15); zero cols 144..159
        #pragma unroll
        for (int ct = 0; ct < 9; ++ct)
            #pragma unroll
            for (int r = 0; r < 4; ++r)
                P[(g * 4 + r) * 168 + ct * 16 + l15] =
                    __float2bfloat16(acc[ct][r] * sm[r]);
        #pragma unroll
        for (int r = 0; r < 4; ++r)
            P[(g * 4 + r) * 168 + 144 + l15] = __float2bfloat16(0.f);

        // PV: O strip = P[16][160] @ V[160][64]
        #pragma unroll
        for (int co = 0; co < 4; ++co) {
            f32x4 o = {0.f, 0.f, 0.f, 0.f};
            #pragma unroll
            for (int kc = 0; kc < 5; ++kc) {
                const bf16x8 pa = *(const bf16x8*)(P + l15 * 168 + kc * 32 + g * 8);
                const bf16x8 vv = *(const bf16x8*)(Vt + (co * 16 + l15) * 168 + kc * 32 + g * 8);
                o = __builtin_amdgcn_mfma_f32_16x16x32_bf16(pa, vv, o, 0, 0, 0);
            }
            #pragma unroll
            for (int r = 0; r < 4; ++r) {
                const int orow = rt * 16 + g * 4 + r;
                if (orow < S_)
                    qb[base + (size_t)orow * E_ + co * 16 + l15] =
                        __float2bfloat16(o[r]);
            }
        }
    }
}

// mean-pool tokens 1..128 -> bf16 h[B,E]
__global__ __launch_bounds__(128)
void pool_kernel(const float* __restrict__ X2, bf16* __restrict__ Hout) {
    const int b = blockIdx.x, e = threadIdx.x;
    float acc = 0.f;
    for (int s = 1; s < S_; ++s) acc += X2[((size_t)b * S_ + s) * E_ + e];
    Hout[(size_t)b * E_ + e] = __float2bfloat16(acc * (1.f / 128.f));
}

// reduce split-K partials [4][128][1024] -> out[128][1000] (+bias)
__global__ __launch_bounds__(256)
void splitk_reduce(const float* __restrict__ part, const float* __restrict__ bias,
                   float* __restrict__ out) {
    const int i = blockIdx.x * 256 + threadIdx.x;
    if (i >= B_ * CAT_) return;
    const int m = i / CAT_, n = i - m * CAT_;
    float v = bias[n];
    #pragma unroll
    for (int z = 0; z < 4; ++z) v += part[(size_t)z * 131072 + m * 1024 + n];
    out[i] = v;
}

// ---------------------------------------------------------------------------
extern "C" void kernel_launch(void* const* d_in, const int* in_sizes, int n_in,
                              void* d_out, int out_size, void* d_ws, size_t ws_size,
                              hipStream_t stream) {
    const int* cat_arr      = (const int*)d_in[0];
    const int* dt_arr       = (const int*)d_in[1];
    const int* amount_arr   = (const int*)d_in[2];
    const int* id_arr       = (const int*)d_in[3];
    const float* id_table   = (const float*)d_in[4];
    const float* cat_table  = (const float*)d_in[5];
    const float* amount_tab = (const float*)d_in[6];
    const float* dt_table   = (const float*)d_in[7];
    const float* Wq = (const float*)d_in[8];  const float* bq = (const float*)d_in[9];
    const float* Wk = (const float*)d_in[10]; const float* bk = (const float*)d_in[11];
    const float* Wv = (const float*)d_in[12]; const float* bv = (const float*)d_in[13];
    const float* Wo = (const float*)d_in[14]; const float* bo = (const float*)d_in[15];
    const float* ln1_g = (const float*)d_in[16]; const float* ln1_b = (const float*)d_in[17];
    const float* W1 = (const float*)d_in[18]; const float* b1 = (const float*)d_in[19];
    const float* W2 = (const float*)d_in[20]; const float* b2 = (const float*)d_in[21];
    const float* ln2_g = (const float*)d_in[22]; const float* ln2_b = (const float*)d_in[23];
    const float* lin1_W = (const float*)d_in[24]; const float* lin1_b = (const float*)d_in[25];
    const float* lin2_W = (const float*)d_in[26]; const float* lin2_b = (const float*)d_in[27];
    float* out = (float*)d_out;
    float* ws = (float*)d_ws;

    // Workspace (floats), total ~23.9 MiB:
    //   X[ME] | C0 bf16[ME] | D0 bf16[ME] | E0 bf16[ME] | Wd | bias1024 | catb | amtb
    const size_t ME = (size_t)M_ * E_;           // 2,113,536
    float* X  = ws;                               // f32 x -> x1 -> x2 (in-place)
    bf16* C0  = (bf16*)(ws + ME);                 // Kb -> X1b -> F1b
    bf16* D0  = (bf16*)(ws + ME + ME / 2);        // Qb -> Ob -> hbb/a1b
    bf16* E0  = (bf16*)(ws + 2 * ME);             // Vb -> (f32 prt)
    bf16* Wd  = (bf16*)(ws + 2 * ME + ME / 2);    // 1,277,952 bf16
    float* bias1024 = ws + 2 * ME + ME / 2 + 638976;
    bf16* catb = (bf16*)(bias1024 + 1024);        // [1000][128] bf16
    bf16* amtb = catb + 128000;                   // [100][128] bf16
    bf16* hbb = D0;                               // [128][128]
    bf16* a1b = D0 + 16384;                       // [128][1024]
    float* prt = (float*)E0;                      // [4][128][1024] f32 (2 MiB)

    prep_kernel<<<dim3(16, 16, 10), 256, 0, stream>>>(
        Wq, Wk, Wv, Wo, W1, W2, lin1_W, lin2_W, lin1_b,
        cat_table, amount_tab, Wd, bias1024, catb, amtb);

    embed_kernel<<<M_ / 2, 256, 0, stream>>>(cat_arr, dt_arr, amount_arr, id_arr,
                                             id_table, catb, amtb, dt_table, X);

    // Fused QKV from f32 X: sel 0->Q(D0), 1->K(C0), 2->V(E0)
    gemm_mfma<false,false,false,false,true,false,true,true>
        <<<dim3(M_ / 64, 3), 256, 0, stream>>>(
        X, Wd, bq, bk, bv, nullptr, nullptr, D0, C0, E0, nullptr, nullptr,
        128, 128, 128);

    attn_mfma<<<B_ * H_ * 2, 256, 0, stream>>>(D0, C0, E0);   // Ob -> D0

    const dim3 gE(M_ / 64, 1);
    // X1 = LN1(X + Ob@Wo + bo): f32 in-place X, bf16 X1b -> C0 (K dead)
    gemm_mfma<false,true,true,true,true,false,false,false><<<gE, 256, 0, stream>>>(
        D0, Wd + 49152, bo, nullptr, nullptr, X, X, C0, nullptr, nullptr,
        ln1_g, ln1_b, 128, 128, 128);
    // F1b = relu(X1b@W1 + b1) -> C0 in-place (block-row-aligned)
    gemm_mfma<true,false,false,false,true,false,false,false><<<gE, 256, 0, stream>>>(
        C0, Wd + 65536, b1, nullptr, nullptr, nullptr, nullptr, C0, nullptr, nullptr,
        nullptr, nullptr, 128, 128, 128);
    // X2 = LN2(X1 + F1b@W2 + b2): f32 in-place X
    gemm_mfma<false,true,true,true,false,false,false,false><<<gE, 256, 0, stream>>>(
        C0, Wd + 81920, b2, nullptr, nullptr, X, X, nullptr, nullptr, nullptr,
        ln2_g, ln2_b, 128, 128, 128);

    pool_kernel<<<B_, 128, 0, stream>>>(X, hbb);

    // a1b = relu(hbb@lin1 + b) [128][1024]
    gemm_mfma<true,false,false,false,true,false,false,false>
        <<<dim3(2, 8), 256, 0, stream>>>(
        hbb, Wd + 98304, bias1024, nullptr, nullptr, nullptr, nullptr, a1b,
        nullptr, nullptr, nullptr, nullptr, 128, 1024, 1024);
    // prt[z] = a1b@lin2 partials (K=1024 split 4 ways)
    gemm_mfma<false,false,false,true,false,true,false,false>
        <<<dim3(2, 8, 4), 256, 0, stream>>>(
        a1b, Wd + 229376, nullptr, nullptr, nullptr, nullptr, prt, nullptr,
        nullptr, nullptr, nullptr, nullptr, 1024, 1024, 1024);
    splitk_reduce<<<(B_ * CAT_ + 255) / 256, 256, 0, stream>>>(prt, lin2_b, out);
}

// Round 9
// 124.759 us; speedup vs baseline: 3.2179x; 1.1956x over previous
//
#include <hip/hip_runtime.h>
#include <hip/hip_bf16.h>

#define B_ 128
#define L_ 128
#define J_ 64
#define E_ 128
#define H_ 2
#define HD 64
#define S_ 129          // L+1
#define M_ (B_ * S_)    // 16512 tokens
#define CAT_ 1000
#define LN_EPS 1e-5f

typedef __attribute__((ext_vector_type(8))) short bf16x8;
typedef __attribute__((ext_vector_type(4))) float f32x4;
typedef __hip_bfloat16 bf16;

__device__ inline float bf2f(unsigned short u) {
    union { unsigned int i; float f; } v; v.i = (unsigned int)u << 16; return v.f;
}
__device__ inline unsigned short f2bu(float f) {
    __hip_bfloat16 h = __float2bfloat16(f);
    return *reinterpret_cast<unsigned short*>(&h);
}

// ---------------------------------------------------------------------------
// prep: transpose+convert weights to bf16 Bt[N][K]; pad lin1/lin2; pad bias;
// z=8/9: convert cat/amount tables to bf16 (row-layout unchanged).
// Wd bf16 offsets: q=0 k=16384 v=32768 o=49152 w1=65536 w2=81920
//                  lin1=98304 ([1024][128]) lin2=229376 ([1024][1024])
// ---------------------------------------------------------------------------
__global__ __launch_bounds__(256)
void prep_kernel(const float* __restrict__ Wq, const float* __restrict__ Wk,
                 const float* __restrict__ Wv, const float* __restrict__ Wo,
                 const float* __restrict__ W1, const float* __restrict__ W2,
                 const float* __restrict__ lin1W, const float* __restrict__ lin2W,
                 const float* __restrict__ lin1b,
                 const float* __restrict__ cat_table, const float* __restrict__ amount_table,
                 bf16* __restrict__ Wd, float* __restrict__ bias1024,
                 bf16* __restrict__ catb, bf16* __restrict__ amtb) {
    const int z = blockIdx.z;
    const int tid = threadIdx.x;
    if (z == 8) {   // cat_table -> bf16, 128000 elems
        const int gid = (blockIdx.x * 16 + blockIdx.y) * 256 + tid;
        for (int i = gid; i < 1000 * 128; i += 65536)
            catb[i] = __float2bfloat16(cat_table[i]);
        return;
    }
    if (z == 9) {   // amount_table -> bf16, 12800 elems
        const int gid = (blockIdx.x * 16 + blockIdx.y) * 256 + tid;
        for (int i = gid; i < 100 * 128; i += 65536)
            amtb[i] = __float2bfloat16(amount_table[i]);
        return;
    }
    const float* src; bf16* dst; int Kd, Nd, sK, sN;
    switch (z) {
        case 0: src = Wq;    dst = Wd;          Kd = 128;  Nd = 128;  sK = 128;  sN = 128;  break;
        case 1: src = Wk;    dst = Wd + 16384;  Kd = 128;  Nd = 128;  sK = 128;  sN = 128;  break;
        case 2: src = Wv;    dst = Wd + 32768;  Kd = 128;  Nd = 128;  sK = 128;  sN = 128;  break;
        case 3: src = Wo;    dst = Wd + 49152;  Kd = 128;  Nd = 128;  sK = 128;  sN = 128;  break;
        case 4: src = W1;    dst = Wd + 65536;  Kd = 128;  Nd = 128;  sK = 128;  sN = 128;  break;
        case 5: src = W2;    dst = Wd + 81920;  Kd = 128;  Nd = 128;  sK = 128;  sN = 128;  break;
        case 6: src = lin1W; dst = Wd + 98304;  Kd = 128;  Nd = 1024; sK = 128;  sN = 1000; break;
        default:src = lin2W; dst = Wd + 229376; Kd = 1024; Nd = 1024; sK = 1000; sN = 1000; break;
    }
    if (z == 7 && blockIdx.x == 0 && blockIdx.y == 0) {
        for (int i = tid; i < 1024; i += 256)
            bias1024[i] = (i < 1000) ? lin1b[i] : 0.f;
    }
    const int k0 = blockIdx.x * 64, n0 = blockIdx.y * 64;
    if (k0 >= Kd || n0 >= Nd) return;
    __shared__ float t[64][65];
    const int c = tid & 63, r0 = tid >> 6;
    #pragma unroll 4
    for (int i = 0; i < 16; ++i) {
        const int r = r0 + i * 4;
        const int gk = k0 + r, gn = n0 + c;
        t[r][c] = (gk < sK && gn < sN) ? src[(size_t)gk * sN + gn] : 0.f;
    }
    __syncthreads();
    #pragma unroll 4
    for (int i = 0; i < 16; ++i) {
        const int r = r0 + i * 4;
        dst[(size_t)(n0 + r) * Kd + (k0 + c)] = __float2bfloat16(t[c][r]);
    }
}

// ---------------------------------------------------------------------------
// Embedding v3: 2 tokens/block; per token 4 j-groups x 32 lanes x 4 elems.
// ---------------------------------------------------------------------------
__global__ __launch_bounds__(256)
void embed_kernel(const int* __restrict__ cat_arr, const int* __restrict__ dt_arr,
                  const int* __restrict__ amount_arr, const int* __restrict__ id_arr,
                  const float* __restrict__ id_table, const bf16* __restrict__ catb,
                  const bf16* __restrict__ amtb, const float* __restrict__ dt_table,
                  float* __restrict__ x) {
    __shared__ int cs[2][64];
    __shared__ int as_[2][64];
    __shared__ f32x4 red[2][4][32];
    const int tid = threadIdx.x;
    const int g2 = tid >> 7;              // token slot in block
    const int t7 = tid & 127;
    const int jg = t7 >> 5;               // j-group 0..3
    const int lg = t7 & 31;               // elems lg*4 .. lg*4+3
    const int t = blockIdx.x * 2 + g2;
    const int b = t / S_, s = t - b * S_;

    if (s > 0) {
        const int base = (b * L_ + (s - 1)) * J_;
        if (t7 < 64) cs[g2][t7] = cat_arr[base + t7];
        else         as_[g2][t7 - 64] = amount_arr[base + t7 - 64];
    }
    __syncthreads();

    f32x4 acc = {0.f, 0.f, 0.f, 0.f};
    if (s > 0) {
        #pragma unroll
        for (int jj = 0; jj < 16; ++jj) {
            const int j = jg * 16 + jj;
            const int c = cs[g2][j];
            const float m = (c != CAT_) ? 1.f : 0.f;
            const int ci = (c != CAT_) ? c : 0;
            const ushort4 cu = *(const ushort4*)(catb + (size_t)ci * E_ + lg * 4);
            const ushort4 au = *(const ushort4*)(amtb + (size_t)as_[g2][j] * E_ + lg * 4);
            acc[0] = fmaf(m, bf2f(cu.x) + bf2f(au.x), acc[0]);
            acc[1] = fmaf(m, bf2f(cu.y) + bf2f(au.y), acc[1]);
            acc[2] = fmaf(m, bf2f(cu.z) + bf2f(au.z), acc[2]);
            acc[3] = fmaf(m, bf2f(cu.w) + bf2f(au.w), acc[3]);
        }
    }
    red[g2][jg][lg] = acc;
    __syncthreads();

    if (jg == 0) {
        const size_t off = (size_t)t * E_ + lg * 4;
        if (s == 0) {
            *(float4*)(x + off) =
                *(const float4*)(id_table + (size_t)id_arr[b] * E_ + lg * 4);
        } else {
            const f32x4 a0 = red[g2][0][lg], a1 = red[g2][1][lg];
            const f32x4 a2 = red[g2][2][lg], a3 = red[g2][3][lg];
            const float4 dv = *(const float4*)(
                dt_table + (size_t)dt_arr[b * L_ + s - 1] * E_ + lg * 4);
            float4 o;
            o.x = a0[0] + a1[0] + a2[0] + a3[0] + dv.x;
            o.y = a0[1] + a1[1] + a2[1] + a3[1] + dv.y;
            o.z = a0[2] + a1[2] + a2[2] + a3[2] + dv.z;
            o.w = a0[3] + a1[3] + a2[3] + a3[3] + dv.w;
            *(float4*)(x + off) = o;
        }
    }
}

// ---------------------------------------------------------------------------
// bf16 MFMA GEMM (QKV / lin1 / lin2 paths)
// ---------------------------------------------------------------------------
template<bool RELU, bool LN, bool HASRES, bool OF32, bool OBF16, bool SPLITK,
         bool AF32, bool QKV>
__global__ __launch_bounds__(256)
void gemm_mfma(const void* __restrict__ Av, const bf16* __restrict__ Bt,
               const float* __restrict__ bias, const float* __restrict__ bias2,
               const float* __restrict__ bias3, const float* __restrict__ resid,
               float* __restrict__ Cf, bf16* __restrict__ Cb,
               bf16* __restrict__ Cb2, bf16* __restrict__ Cb3,
               const float* __restrict__ lng, const float* __restrict__ lnb,
               int K, int Nstride, int Nstore) {
    __shared__ bf16x8 Al[64 * 16];    // 16 KiB
    __shared__ bf16x8 Bl[128 * 16];   // 32 KiB
    const int tid = threadIdx.x;
    const int m0 = blockIdx.x * 64;
    const int n0 = QKV ? 0 : blockIdx.y * 128;
    const int w = tid >> 6, l = tid & 63;
    const int l15 = l & 15, g = l >> 4;
    f32x4 acc[8] = {};

    const bf16* BtX = Bt;
    const float* biasX = bias;
    bf16* CbX = Cb;
    if (QKV) {
        const int sel = blockIdx.y;
        BtX = Bt + sel * 16384;
        biasX = (sel == 0) ? bias : ((sel == 1) ? bias2 : bias3);
        CbX = (sel == 0) ? Cb : ((sel == 1) ? Cb2 : Cb3);
    }

    const int z = SPLITK ? blockIdx.z : 0;
    const int ksz = SPLITK ? (K / (int)gridDim.z) : K;
    const int kbeg = z * ksz;

    for (int kc = kbeg; kc < kbeg + ksz; kc += 128) {
        #pragma unroll
        for (int i = 0; i < 4; ++i) {
            const int lin = i * 256 + tid;
            const int r = lin >> 4, u = lin & 15;
            bf16x8 av;
            if (AF32) {
                const float* Af = (const float*)Av;
                const float4 f0 = *(const float4*)(Af + (size_t)(m0 + r) * K + kc + u * 8);
                const float4 f1 = *(const float4*)(Af + (size_t)(m0 + r) * K + kc + u * 8 + 4);
                av[0] = (short)f2bu(f0.x); av[1] = (short)f2bu(f0.y);
                av[2] = (short)f2bu(f0.z); av[3] = (short)f2bu(f0.w);
                av[4] = (short)f2bu(f1.x); av[5] = (short)f2bu(f1.y);
                av[6] = (short)f2bu(f1.z); av[7] = (short)f2bu(f1.w);
            } else {
                const bf16* Ab = (const bf16*)Av;
                av = *(const bf16x8*)(Ab + (size_t)(m0 + r) * K + kc + u * 8);
            }
            Al[r * 16 + (u ^ (r & 7))] = av;
        }
        #pragma unroll
        for (int i = 0; i < 8; ++i) {
            const int lin = i * 256 + tid;
            const int r = lin >> 4, u = lin & 15;
            Bl[r * 16 + (u ^ (r & 7))] =
                *(const bf16x8*)(BtX + (size_t)(n0 + r) * K + kc + u * 8);
        }
        __syncthreads();
        const int mr = w * 16 + l15;
        #pragma unroll
        for (int s = 0; s < 4; ++s) {
            const int ua = s * 4 + g;
            const bf16x8 a = Al[mr * 16 + (ua ^ (mr & 7))];
            #pragma unroll
            for (int nf = 0; nf < 8; ++nf) {
                const int nr = nf * 16 + l15;
                const bf16x8 b = Bl[nr * 16 + (ua ^ (nr & 7))];
                acc[nf] = __builtin_amdgcn_mfma_f32_16x16x32_bf16(a, b, acc[nf], 0, 0, 0);
            }
        }
        __syncthreads();
    }

    #pragma unroll
    for (int fr = 0; fr < 4; ++fr) {
        const int grow = m0 + w * 16 + g * 4 + fr;
        float v[8];
        float s1 = 0.f, s2 = 0.f;
        #pragma unroll
        for (int nf = 0; nf < 8; ++nf) {
            const int col = n0 + nf * 16 + l15;
            float xv = acc[nf][fr];
            if (!SPLITK && col < Nstore) xv += biasX[col];
            if (HASRES) xv += resid[(size_t)grow * Nstride + col];
            if (RELU) xv = fmaxf(xv, 0.f);
            v[nf] = xv;
            if (LN) { s1 += xv; s2 += xv * xv; }
        }
        if (LN) {
            #pragma unroll
            for (int off = 1; off < 16; off <<= 1) {
                s1 += __shfl_xor(s1, off);
                s2 += __shfl_xor(s2, off);
            }
            const float mu = s1 * (1.f / 128.f);
            const float rstd = rsqrtf(s2 * (1.f / 128.f) - mu * mu + LN_EPS);
            #pragma unroll
            for (int nf = 0; nf < 8; ++nf) {
                const int col = n0 + nf * 16 + l15;
                v[nf] = (v[nf] - mu) * rstd * lng[col] + lnb[col];
            }
        }
        float* Cfp = SPLITK ? (Cf + (size_t)z * (gridDim.x * 64) * Nstride) : Cf;
        #pragma unroll
        for (int nf = 0; nf < 8; ++nf) {
            const int col = n0 + nf * 16 + l15;
            if (col < Nstore) {
                if (OF32)  Cfp[(size_t)grow * Nstride + col] = v[nf];
                if (OBF16) CbX[(size_t)grow * Nstride + col] = __float2bfloat16(v[nf]);
            }
        }
    }
}

// ---------------------------------------------------------------------------
// Fused encoder tail: per 64-row block, X2 = LN2(X1 + relu(X1@W1+b1)@W2+b2),
// X1 = LN1(X + O@Wo + bo). All E=128 GEMMs are row-block-local, so the whole
// chain runs in one kernel: 3 weight stagings into Bl (barrier-separated),
// x1 kept in registers (epilogue layout identical across steps), activations
// recycled through wave-local 16-row stripes of Al (no barrier needed).
// ---------------------------------------------------------------------------
__global__ __launch_bounds__(256)
void encoder_tail(const bf16* __restrict__ Ob, const bf16* __restrict__ Wd,
                  const float* __restrict__ bo, const float* __restrict__ b1,
                  const float* __restrict__ b2,
                  const float* __restrict__ ln1g, const float* __restrict__ ln1b,
                  const float* __restrict__ ln2g, const float* __restrict__ ln2b,
                  float* __restrict__ X) {
    __shared__ bf16x8 Al[64 * 16];    // 16 KiB
    __shared__ bf16x8 Bl[128 * 16];   // 32 KiB
    const int tid = threadIdx.x;
    const int m0 = blockIdx.x * 64;
    const int w = tid >> 6, l = tid & 63;
    const int l15 = l & 15, g = l >> 4;
    bf16* Alb = (bf16*)Al;

    // stage A = O tile, B = Wo
    #pragma unroll
    for (int i = 0; i < 4; ++i) {
        const int lin = i * 256 + tid;
        const int r = lin >> 4, u = lin & 15;
        Al[r * 16 + (u ^ (r & 7))] =
            *(const bf16x8*)(Ob + (size_t)(m0 + r) * E_ + u * 8);
    }
    #pragma unroll
    for (int i = 0; i < 8; ++i) {
        const int lin = i * 256 + tid;
        const int r = lin >> 4, u = lin & 15;
        Bl[r * 16 + (u ^ (r & 7))] =
            *(const bf16x8*)(Wd + 49152 + (size_t)r * E_ + u * 8);
    }
    __syncthreads();

    const int mr = w * 16 + l15;
    f32x4 acc[8];

    // ---- step 1: O@Wo ----
    #pragma unroll
    for (int nf = 0; nf < 8; ++nf) acc[nf] = f32x4{0.f, 0.f, 0.f, 0.f};
    #pragma unroll
    for (int s = 0; s < 4; ++s) {
        const int ua = s * 4 + g;
        const bf16x8 a = Al[mr * 16 + (ua ^ (mr & 7))];
        #pragma unroll
        for (int nf = 0; nf < 8; ++nf) {
            const int nr = nf * 16 + l15;
            acc[nf] = __builtin_amdgcn_mfma_f32_16x16x32_bf16(
                a, Bl[nr * 16 + (ua ^ (nr & 7))], acc[nf], 0, 0, 0);
        }
    }
    // ep1: x1 = LN1(acc + bo + X); keep f32 in regs; write bf16 to Al
    float x1[8][4];
    #pragma unroll
    for (int fr = 0; fr < 4; ++fr) {
        const int rloc = w * 16 + g * 4 + fr;
        const int grow = m0 + rloc;
        float s1 = 0.f, s2 = 0.f;
        float v[8];
        #pragma unroll
        for (int nf = 0; nf < 8; ++nf) {
            const int col = nf * 16 + l15;
            const float xv = acc[nf][fr] + bo[col] + X[(size_t)grow * E_ + col];
            v[nf] = xv; s1 += xv; s2 += xv * xv;
        }
        #pragma unroll
        for (int off = 1; off < 16; off <<= 1) {
            s1 += __shfl_xor(s1, off);
            s2 += __shfl_xor(s2, off);
        }
        const float mu = s1 * (1.f / 128.f);
        const float rstd = rsqrtf(s2 * (1.f / 128.f) - mu * mu + LN_EPS);
        #pragma unroll
        for (int nf = 0; nf < 8; ++nf) {
            const int col = nf * 16 + l15;
            const float xo = (v[nf] - mu) * rstd * ln1g[col] + ln1b[col];
            x1[nf][fr] = xo;
            const int u = col >> 3;
            Alb[(rloc * 16 + (u ^ (rloc & 7))) * 8 + (col & 7)] = __float2bfloat16(xo);
        }
    }

    // ---- step 2: relu(x1@W1 + b1) ----
    __syncthreads();                       // all waves done reading Bl(Wo)
    #pragma unroll
    for (int i = 0; i < 8; ++i) {
        const int lin = i * 256 + tid;
        const int r = lin >> 4, u = lin & 15;
        Bl[r * 16 + (u ^ (r & 7))] =
            *(const bf16x8*)(Wd + 65536 + (size_t)r * E_ + u * 8);
    }
    __syncthreads();
    #pragma unroll
    for (int nf = 0; nf < 8; ++nf) acc[nf] = f32x4{0.f, 0.f, 0.f, 0.f};
    #pragma unroll
    for (int s = 0; s < 4; ++s) {
        const int ua = s * 4 + g;
        const bf16x8 a = Al[mr * 16 + (ua ^ (mr & 7))];
        #pragma unroll
        for (int nf = 0; nf < 8; ++nf) {
            const int nr = nf * 16 + l15;
            acc[nf] = __builtin_amdgcn_mfma_f32_16x16x32_bf16(
                a, Bl[nr * 16 + (ua ^ (nr & 7))], acc[nf], 0, 0, 0);
        }
    }
    #pragma unroll
    for (int fr = 0; fr < 4; ++fr) {
        const int rloc = w * 16 + g * 4 + fr;
        #pragma unroll
        for (int nf = 0; nf < 8; ++nf) {
            const int col = nf * 16 + l15;
            const float f = fmaxf(acc[nf][fr] + b1[col], 0.f);
            const int u = col >> 3;
            Alb[(rloc * 16 + (u ^ (rloc & 7))) * 8 + (col & 7)] = __float2bfloat16(f);
        }
    }

    // ---- step 3: LN2(x1 + f1@W2 + b2) -> X ----
    __syncthreads();
    #pragma unroll
    for (int i = 0; i < 8; ++i) {
        const int lin = i * 256 + tid;
        const int r = lin >> 4, u = lin & 15;
        Bl[r * 16 + (u ^ (r & 7))] =
            *(const bf16x8*)(Wd + 81920 + (size_t)r * E_ + u * 8);
    }
    __syncthreads();
    #pragma unroll
    for (int nf = 0; nf < 8; ++nf) acc[nf] = f32x4{0.f, 0.f, 0.f, 0.f};
    #pragma unroll
    for (int s = 0; s < 4; ++s) {
        const int ua = s * 4 + g;
        const bf16x8 a = Al[mr * 16 + (ua ^ (mr & 7))];
        #pragma unroll
        for (int nf = 0; nf < 8; ++nf) {
            const int nr = nf * 16 + l15;
            acc[nf] = __builtin_amdgcn_mfma_f32_16x16x32_bf16(
                a, Bl[nr * 16 + (ua ^ (nr & 7))], acc[nf], 0, 0, 0);
        }
    }
    #pragma unroll
    for (int fr = 0; fr < 4; ++fr) {
        const int grow = m0 + w * 16 + g * 4 + fr;
        float s1 = 0.f, s2 = 0.f;
        float v[8];
        #pragma unroll
        for (int nf = 0; nf < 8; ++nf) {
            const int col = nf * 16 + l15;
            const float xv = acc[nf][fr] + b2[col] + x1[nf][fr];
            v[nf] = xv; s1 += xv; s2 += xv * xv;
        }
        #pragma unroll
        for (int off = 1; off < 16; off <<= 1) {
            s1 += __shfl_xor(s1, off);
            s2 += __shfl_xor(s2, off);
        }
        const float mu = s1 * (1.f / 128.f);
        const float rstd = rsqrtf(s2 * (1.f / 128.f) - mu * mu + LN_EPS);
        #pragma unroll
        for (int nf = 0; nf < 8; ++nf) {
            const int col = nf * 16 + l15;
            X[(size_t)grow * E_ + col] = (v[nf] - mu) * rstd * ln2g[col] + ln2b[col];
        }
    }
}

// ---------------------------------------------------------------------------
// MFMA attention v2 (unchanged from round 8)
// ---------------------------------------------------------------------------
__global__ __launch_bounds__(256)
void attn_mfma(bf16* __restrict__ qb, const bf16* __restrict__ kb,
               const bf16* __restrict__ vb) {
    __shared__ __align__(16) bf16x8 Ks[144 * 8];      // 18 KiB, swizzled
    __shared__ __align__(16) bf16  Vt[64 * 168];      // 21 KiB, V^T
    __shared__ __align__(16) bf16  Pb[4][16 * 168];   // 21 KiB, per-wave P
    const int tid = threadIdx.x;
    const int w = tid >> 6, l = tid & 63;
    const int l15 = l & 15, g = l >> 4;
    const int blk = blockIdx.x;
    const int half = blk & 1;
    const int h = (blk >> 1) & (H_ - 1);
    const int b = blk >> 2;
    const size_t base = ((size_t)b * S_) * E_ + h * HD;

    for (int idx = tid; idx < 144 * 8; idx += 256) {
        const int r = idx >> 3, u = idx & 7;
        bf16x8 kv = {0, 0, 0, 0, 0, 0, 0, 0};
        if (r < S_) kv = *(const bf16x8*)(kb + base + (size_t)r * E_ + u * 8);
        Ks[r * 8 + (u ^ (r & 7))] = kv;
    }
    for (int idx = tid; idx < 168 * 64; idx += 256) {
        const int t = idx >> 6, d = idx & 63;
        Vt[d * 168 + t] = (t < S_) ? vb[base + (size_t)t * E_ + d]
                                   : __float2bfloat16(0.f);
    }
    __syncthreads();

    bf16* P = Pb[w];
    for (int rt = (half ? 5 : 0) + w; rt < (half ? 9 : 5); rt += 4) {
        const int qr0 = rt * 16 + l15;
        const int qrow = (qr0 < S_) ? qr0 : (S_ - 1);
        const bf16x8 aq0 = *(const bf16x8*)(qb + base + (size_t)qrow * E_ + g * 8);
        const bf16x8 aq1 = *(const bf16x8*)(qb + base + (size_t)qrow * E_ + 32 + g * 8);

        f32x4 acc[9];
        #pragma unroll
        for (int ct = 0; ct < 9; ++ct) {
            const int kr = ct * 16 + l15;
            f32x4 a = {0.f, 0.f, 0.f, 0.f};
            a = __builtin_amdgcn_mfma_f32_16x16x32_bf16(
                    aq0, Ks[kr * 8 + (g ^ (kr & 7))], a, 0, 0, 0);
            a = __builtin_amdgcn_mfma_f32_16x16x32_bf16(
                    aq1, Ks[kr * 8 + ((4 + g) ^ (kr & 7))], a, 0, 0, 0);
            acc[ct] = a;
        }

        const bool tail = (l15 != 0);
        float mx[4] = {-1e30f, -1e30f, -1e30f, -1e30f};
        #pragma unroll
        for (int ct = 0; ct < 9; ++ct)
            #pragma unroll
            for (int r = 0; r < 4; ++r) {
                const float v = acc[ct][r] * 0.125f;
                acc[ct][r] = v;
                if (ct < 8 || !tail) mx[r] = fmaxf(mx[r], v);
            }
        #pragma unroll
        for (int r = 0; r < 4; ++r)
            #pragma unroll
            for (int off = 1; off < 16; off <<= 1)
                mx[r] = fmaxf(mx[r], __shfl_xor(mx[r], off));
        float sm[4] = {0.f, 0.f, 0.f, 0.f};
        #pragma unroll
        for (int ct = 0; ct < 9; ++ct)
            #pragma unroll
            for (int r = 0; r < 4; ++r) {
                const float p = (ct < 8 || !tail) ? __expf(acc[ct][r] - mx[r]) : 0.f;
                acc[ct][r] = p;
                sm[r] += p;
            }
        #pragma unroll
        for (int r = 0; r < 4; ++r) {
            #pragma unroll
            for (int off = 1; off < 16; off <<= 1)
                sm[r] += __shfl_xor(sm[r], off);
            sm[r] = 1.f / sm[r];
        }

        #pragma unroll
        for (int ct = 0; ct < 9; ++ct)
            #pragma unroll
            for (int r = 0; r < 4; ++r)
                P[(g * 4 + r) * 168 + ct * 16 + l15] =
                    __float2bfloat16(acc[ct][r] * sm[r]);
        #pragma unroll
        for (int r = 0; r < 4; ++r)
            P[(g * 4 + r) * 168 + 144 + l15] = __float2bfloat16(0.f);

        #pragma unroll
        for (int co = 0; co < 4; ++co) {
            f32x4 o = {0.f, 0.f, 0.f, 0.f};
            #pragma unroll
            for (int kc = 0; kc < 5; ++kc) {
                const bf16x8 pa = *(const bf16x8*)(P + l15 * 168 + kc * 32 + g * 8);
                const bf16x8 vv = *(const bf16x8*)(Vt + (co * 16 + l15) * 168 + kc * 32 + g * 8);
                o = __builtin_amdgcn_mfma_f32_16x16x32_bf16(pa, vv, o, 0, 0, 0);
            }
            #pragma unroll
            for (int r = 0; r < 4; ++r) {
                const int orow = rt * 16 + g * 4 + r;
                if (orow < S_)
                    qb[base + (size_t)orow * E_ + co * 16 + l15] =
                        __float2bfloat16(o[r]);
            }
        }
    }
}

// mean-pool tokens 1..128 -> bf16 h[B,E]
__global__ __launch_bounds__(128)
void pool_kernel(const float* __restrict__ X2, bf16* __restrict__ Hout) {
    const int b = blockIdx.x, e = threadIdx.x;
    float acc = 0.f;
    for (int s = 1; s < S_; ++s) acc += X2[((size_t)b * S_ + s) * E_ + e];
    Hout[(size_t)b * E_ + e] = __float2bfloat16(acc * (1.f / 128.f));
}

// reduce split-K partials [8][128][1024] -> out[128][1000] (+bias)
__global__ __launch_bounds__(256)
void splitk_reduce(const float* __restrict__ part, const float* __restrict__ bias,
                   float* __restrict__ out) {
    const int i = blockIdx.x * 256 + threadIdx.x;
    if (i >= B_ * CAT_) return;
    const int m = i / CAT_, n = i - m * CAT_;
    float v = bias[n];
    #pragma unroll
    for (int z = 0; z < 8; ++z) v += part[(size_t)z * 131072 + m * 1024 + n];
    out[i] = v;
}

// ---------------------------------------------------------------------------
extern "C" void kernel_launch(void* const* d_in, const int* in_sizes, int n_in,
                              void* d_out, int out_size, void* d_ws, size_t ws_size,
                              hipStream_t stream) {
    const int* cat_arr      = (const int*)d_in[0];
    const int* dt_arr       = (const int*)d_in[1];
    const int* amount_arr   = (const int*)d_in[2];
    const int* id_arr       = (const int*)d_in[3];
    const float* id_table   = (const float*)d_in[4];
    const float* cat_table  = (const float*)d_in[5];
    const float* amount_tab = (const float*)d_in[6];
    const float* dt_table   = (const float*)d_in[7];
    const float* Wq = (const float*)d_in[8];  const float* bq = (const float*)d_in[9];
    const float* Wk = (const float*)d_in[10]; const float* bk = (const float*)d_in[11];
    const float* Wv = (const float*)d_in[12]; const float* bv = (const float*)d_in[13];
    const float* Wo = (const float*)d_in[14]; const float* bo = (const float*)d_in[15];
    const float* ln1_g = (const float*)d_in[16]; const float* ln1_b = (const float*)d_in[17];
    const float* W1 = (const float*)d_in[18]; const float* b1 = (const float*)d_in[19];
    const float* W2 = (const float*)d_in[20]; const float* b2 = (const float*)d_in[21];
    const float* ln2_g = (const float*)d_in[22]; const float* ln2_b = (const float*)d_in[23];
    const float* lin1_W = (const float*)d_in[24]; const float* lin1_b = (const float*)d_in[25];
    const float* lin2_W = (const float*)d_in[26]; const float* lin2_b = (const float*)d_in[27];
    float* out = (float*)d_out;
    float* ws = (float*)d_ws;

    // Workspace (floats), total ~23.9 MiB:
    //   X[ME] | C0 bf16[ME] | D0 bf16[ME] | E0 bf16[ME] | Wd | bias1024 | catb | amtb
    const size_t ME = (size_t)M_ * E_;           // 2,113,536
    float* X  = ws;                               // f32 x -> x2 (in-place)
    bf16* C0  = (bf16*)(ws + ME);                 // Kb
    bf16* D0  = (bf16*)(ws + ME + ME / 2);        // Qb -> Ob -> hbb/a1b
    bf16* E0  = (bf16*)(ws + 2 * ME);             // Vb -> (f32 prt)
    bf16* Wd  = (bf16*)(ws + 2 * ME + ME / 2);    // 1,277,952 bf16
    float* bias1024 = ws + 2 * ME + ME / 2 + 638976;
    bf16* catb = (bf16*)(bias1024 + 1024);        // [1000][128] bf16
    bf16* amtb = catb + 128000;                   // [100][128] bf16
    bf16* hbb = D0;                               // [128][128]
    bf16* a1b = D0 + 16384;                       // [128][1024]
    float* prt = (float*)E0;                      // [8][128][1024] f32 (4 MiB)

    prep_kernel<<<dim3(16, 16, 10), 256, 0, stream>>>(
        Wq, Wk, Wv, Wo, W1, W2, lin1_W, lin2_W, lin1_b,
        cat_table, amount_tab, Wd, bias1024, catb, amtb);

    embed_kernel<<<M_ / 2, 256, 0, stream>>>(cat_arr, dt_arr, amount_arr, id_arr,
                                             id_table, catb, amtb, dt_table, X);

    // Fused QKV from f32 X: sel 0->Q(D0), 1->K(C0), 2->V(E0)
    gemm_mfma<false,false,false,false,true,false,true,true>
        <<<dim3(M_ / 64, 3), 256, 0, stream>>>(
        X, Wd, bq, bk, bv, nullptr, nullptr, D0, C0, E0, nullptr, nullptr,
        128, 128, 128);

    attn_mfma<<<B_ * H_ * 2, 256, 0, stream>>>(D0, C0, E0);   // Ob -> D0

    // Fused tail: X = LN2(X1 + relu(X1@W1+b1)@W2+b2), X1 = LN1(X + Ob@Wo+bo)
    encoder_tail<<<M_ / 64, 256, 0, stream>>>(
        D0, Wd, bo, b1, b2, ln1_g, ln1_b, ln2_g, ln2_b, X);

    pool_kernel<<<B_, 128, 0, stream>>>(X, hbb);

    // a1b = relu(hbb@lin1 + b) [128][1024]
    gemm_mfma<true,false,false,false,true,false,false,false>
        <<<dim3(2, 8), 256, 0, stream>>>(
        hbb, Wd + 98304, bias1024, nullptr, nullptr, nullptr, nullptr, a1b,
        nullptr, nullptr, nullptr, nullptr, 128, 1024, 1024);
    // prt[z] = a1b@lin2 partials (K=1024 split 8 ways)
    gemm_mfma<false,false,false,true,false,true,false,false>
        <<<dim3(2, 8, 8), 256, 0, stream>>>(
        a1b, Wd + 229376, nullptr, nullptr, nullptr, nullptr, prt, nullptr,
        nullptr, nullptr, nullptr, nullptr, 1024, 1024, 1024);
    splitk_reduce<<<(B_ * CAT_ + 255) / 256, 256, 0, stream>>>(prt, lin2_b, out);
}